// Round 1
// 3289.670 us; speedup vs baseline: 1.1265x; 1.1265x over previous
//
#include <hip/hip_runtime.h>
#include <cstddef>

static constexpr int Nn   = 50000;
static constexpr int Ee   = 800000;
static constexpr int LGEe = 1600000;

__device__ __forceinline__ float bf2f(unsigned int u16) {
  return __uint_as_float(u16 << 16);
}
__device__ __forceinline__ unsigned int f2bf(float f) {
  unsigned int u = __float_as_uint(f);
  u += 0x7fffu + ((u >> 16) & 1u);   // RNE
  return u >> 16;
}

// ---------------- CSR build kernels ----------------
__global__ __launch_bounds__(256)
void k_count_direct(const int* __restrict__ idx, int* __restrict__ cnt, int n) {
  int i = blockIdx.x * 256 + threadIdx.x;
  if (i < n) atomicAdd(&cnt[idx[i]], 1);
}
__global__ __launch_bounds__(256)
void k_count_comp(const int* __restrict__ Hrow, const int* __restrict__ dlg,
                  int* __restrict__ cnt, int n) {
  int i = blockIdx.x * 256 + threadIdx.x;
  if (i < n) atomicAdd(&cnt[Hrow[dlg[i]]], 1);
}
__global__ __launch_bounds__(256)
void k_scan1(const int* __restrict__ in, int* __restrict__ out,
             int* __restrict__ bsum, int n) {
  __shared__ int sd[256];
  int tid = threadIdx.x;
  int base = blockIdx.x * 1024 + tid * 4;
  int4 v = {0, 0, 0, 0};
  if (base < n) v = *(const int4*)(in + base);   // n % 4 == 0 for all uses
  int s = v.x + v.y + v.z + v.w;
  sd[tid] = s; __syncthreads();
  for (int off = 1; off < 256; off <<= 1) {
    int t_ = (tid >= off) ? sd[tid - off] : 0; __syncthreads();
    sd[tid] += t_; __syncthreads();
  }
  int excl = sd[tid] - s;
  if (base < n) {
    int4 o; o.x = excl; o.y = o.x + v.x; o.z = o.y + v.y; o.w = o.z + v.z;
    *(int4*)(out + base) = o;
  }
  if (tid == 255) bsum[blockIdx.x] = sd[255];
}
__global__ __launch_bounds__(1024)
void k_scan2(int* __restrict__ b, int nb) {
  __shared__ int sd[1024];
  int tid = threadIdx.x;
  int v = (tid < nb) ? b[tid] : 0;
  sd[tid] = v; __syncthreads();
  for (int off = 1; off < 1024; off <<= 1) {
    int t_ = (tid >= off) ? sd[tid - off] : 0; __syncthreads();
    sd[tid] += t_; __syncthreads();
  }
  if (tid < nb) b[tid] = sd[tid] - v;
}
__global__ __launch_bounds__(256)
void k_scan3(int* __restrict__ out, const int* __restrict__ bsum, int n, int total) {
  int i = blockIdx.x * 256 + threadIdx.x;
  if (i < n) out[i] += bsum[i >> 10];
  if (i == 0) out[n] = total;
}
__global__ __launch_bounds__(256)
void k_fillA(const int* __restrict__ dlg, const int* __restrict__ slg,
             const int* __restrict__ ptr, int* __restrict__ cur,
             int* __restrict__ ent, int n) {
  int m = blockIdx.x * 256 + threadIdx.x;
  if (m >= n) return;
  int d = dlg[m];
  int pos = ptr[d] + atomicAdd(&cur[d], 1);
  ent[pos] = slg[m];
}
__global__ __launch_bounds__(256)
void k_fillB(const int* __restrict__ Hrow, const int* __restrict__ dlg,
             const int* __restrict__ slg, const int* __restrict__ ptrA,
             const int* __restrict__ ptrB, int* __restrict__ cur,
             int* __restrict__ entS, float* __restrict__ entW, int n) {
  int m = blockIdx.x * 256 + threadIdx.x;
  if (m >= n) return;
  int d = dlg[m];
  int seg = Hrow[d];
  int pos = ptrB[seg] + atomicAdd(&cur[seg], 1);
  entS[pos] = slg[m];
  int la = ptrA[d + 1] - ptrA[d];
  entW[pos] = 1.0f / (float)max(la, 1);
}
__global__ __launch_bounds__(256)
void k_fillC(const int* __restrict__ Hrow, const int* __restrict__ ptr,
             int* __restrict__ cur, int* __restrict__ ent, int n) {
  int e = blockIdx.x * 256 + threadIdx.x;
  if (e >= n) return;
  int seg = Hrow[e];
  int pos = ptr[seg] + atomicAdd(&cur[seg], 1);
  ent[pos] = e;
}
__global__ __launch_bounds__(256)
void k_fillD(const int* __restrict__ dstA, const int* __restrict__ srcA,
             const int* __restrict__ ptr, int* __restrict__ cur,
             int* __restrict__ ent, int n) {
  int e = blockIdx.x * 256 + threadIdx.x;
  if (e >= n) return;
  int seg = dstA[e];
  int pos = ptr[seg] + atomicAdd(&cur[seg], 1);
  ent[pos] = srcA[e];
}
__global__ __launch_bounds__(256)
void k_rdeg(const int* __restrict__ ptr, float* __restrict__ r, int n) {
  int i = blockIdx.x * 256 + threadIdx.x;
  if (i < n) r[i] = 1.0f / fmaxf((float)(ptr[i + 1] - ptr[i]), 1.0f);
}

// ---------------- dense GEMM: C[Mx128] = act( rowmul(reluA(A)) @ W ) ----------------
__global__ __launch_bounds__(256)
void k_gemm128(int M, const float* __restrict__ A, int K,
               const float* __restrict__ W, const float* __restrict__ dgA,
               int reluA, int act, float* __restrict__ C)
{
  __shared__ float sA[32][132];
  __shared__ float sW[32][132];
  const int t = threadIdx.x, tr = t >> 4, tc = t & 15;
  const int row0 = blockIdx.x * 128;
  float acc[8][8];
  #pragma unroll
  for (int i = 0; i < 8; ++i)
    #pragma unroll
    for (int j = 0; j < 8; ++j) acc[i][j] = 0.f;

  #pragma unroll 1
  for (int k0 = 0; k0 < K; k0 += 32) {
    __syncthreads();
    #pragma unroll
    for (int j = 0; j < 4; ++j) {
      int idx = t * 4 + j * 1024;
      int r = idx >> 5, kk = idx & 31;
      int gr = row0 + r; if (gr > M - 1) gr = M - 1;
      float4 va = *(const float4*)(A + (size_t)gr * K + k0 + kk);
      if (reluA) {
        va.x = fmaxf(va.x, 0.f); va.y = fmaxf(va.y, 0.f);
        va.z = fmaxf(va.z, 0.f); va.w = fmaxf(va.w, 0.f);
      }
      if (dgA) {
        float sc = dgA[gr];
        va.x *= sc; va.y *= sc; va.z *= sc; va.w *= sc;
      }
      sA[kk + 0][r] = va.x; sA[kk + 1][r] = va.y;
      sA[kk + 2][r] = va.z; sA[kk + 3][r] = va.w;
    }
    #pragma unroll
    for (int j = 0; j < 4; ++j) {
      int idx = t * 4 + j * 1024;
      int kk = idx >> 7, c = idx & 127;
      *(float4*)&sW[kk][c] = *(const float4*)(W + (size_t)(k0 + kk) * 128 + c);
    }
    __syncthreads();
    #pragma unroll
    for (int kk = 0; kk < 32; ++kk) {
      float a[8], w[8];
      *(float4*)&a[0] = *(const float4*)&sA[kk][tr * 8];
      *(float4*)&a[4] = *(const float4*)&sA[kk][tr * 8 + 4];
      *(float4*)&w[0] = *(const float4*)&sW[kk][tc * 8];
      *(float4*)&w[4] = *(const float4*)&sW[kk][tc * 8 + 4];
      #pragma unroll
      for (int i = 0; i < 8; ++i)
        #pragma unroll
        for (int j = 0; j < 8; ++j)
          acc[i][j] = fmaf(a[i], w[j], acc[i][j]);
    }
  }
  #pragma unroll 1
  for (int i = 0; i < 8; ++i) {
    int gr = row0 + tr * 8 + i;
    if (gr >= M) return;
    float o[8];
    #pragma unroll
    for (int j = 0; j < 8; ++j) {
      float vv = acc[i][j];
      if (act == 1)      vv = fmaxf(vv, 0.f);
      else if (act == 2) vv = vv > 0.f ? vv : vv * 0.2f;
      o[j] = vv;
    }
    float* p = C + (size_t)gr * 128 + tc * 8;
    *(float4*)p       = *(const float4*)&o[0];
    *(float4*)(p + 4) = *(const float4*)&o[4];
  }
}

// ---------------- fused TSA1: BUF[e] = bf16( et[e]@Ws + mean_{s in A(e)} et[s] @ Wn ) ----
// 64 segs/block, K = 128 = [direct 64 | gathered 64]. Flattened entry gather
// (8 loads in flight), LDS ent cache, XOR-swizzled sA (conflict-free writes).
__global__ __launch_bounds__(256)
void k_tsa1(const float* __restrict__ et,
            const int* __restrict__ rp, const int* __restrict__ ent,
            const float* __restrict__ Ws, const float* __restrict__ Wn,
            unsigned short* __restrict__ BUF)
{
  __shared__ float sA[128][68];   // phys col = col ^ ((k>>3)&3)  (34816 B)
  __shared__ float sW[32][132];   // 16896 B
  __shared__ int   sEnt[512];     // 2048 B  -> 53760 total, 3 blocks/CU
  const int t = threadIdx.x, wv = t >> 6, lane = t & 63;
  const int tr = t >> 4, tc = t & 15;
  const int seg0 = blockIdx.x * 64;
  const int segbase = seg0 + wv * 16;
  const int fsw = (lane >> 3) & 3;          // write swizzle: same for row=lane and row=64+lane

  // lanes 0..16 hold row pointers of this wave's 16 segments
  int rpv = (lane <= 16) ? rp[segbase + lane] : 0;
  int nxtv = __shfl(rpv, (lane + 1) & 63);
  float invv = 1.f / fmaxf((float)(nxtv - rpv), 1.f);   // valid lanes 0..15

  // cache the block's contiguous ent slice in LDS (coalesced); >512 falls back to global
  const int base = rp[seg0];
  const int cnt  = rp[seg0 + 64] - base;
  const int lim  = cnt < 512 ? cnt : 512;
  for (int i = t; i < lim; i += 256) sEnt[i] = ent[base + i];

  // direct half (k = lane): 16 independent coalesced loads, swizzled writes
  {
    float dv[16];
    #pragma unroll
    for (int i = 0; i < 16; ++i)
      dv[i] = et[(size_t)(segbase + i) * 64 + lane];
    #pragma unroll
    for (int i = 0; i < 16; ++i)
      sA[lane][(wv * 16 + i) ^ fsw] = dv[i];
  }
  __syncthreads();   // sEnt ready

  // gathered half (k = 64+lane): flatten over entries, 8 row-loads in flight.
  // Entries are column-sorted -> register accumulator, one LDS write per column.
  {
    int q0 = __shfl(rpv, 0);
    int q1 = __shfl(rpv, 16);
    int c = 0;                        // wave-uniform column cursor
    int b_next = __shfl(rpv, 1);      // end boundary of column c
    float idg = __shfl(invv, 0);      // 1/max(deg,1) of column c
    float a = 0.f;
    #pragma unroll 1
    for (int j = q0; j < q1; j += 8) {
      float x[8];
      #pragma unroll
      for (int u = 0; u < 8; ++u) {
        int jj = j + u; jj = jj < q1 ? jj : q1 - 1;
        int ix = jj - base;
        int s = (ix < 512) ? sEnt[ix] : ent[jj];
        x[u] = et[(size_t)s * 64 + lane];
      }
      #pragma unroll
      for (int u = 0; u < 8; ++u) {
        int jj = j + u;
        if (jj >= q1) break;
        while (jj >= b_next) {        // column c complete -> flush (handles empties too)
          sA[64 + lane][(wv * 16 + c) ^ fsw] = a * idg;
          a = 0.f;
          ++c;
          b_next = __shfl(rpv, c + 1);
          idg = __shfl(invv, c);
        }
        a += x[u];
      }
    }
    #pragma unroll 1
    for (;;) {                        // flush current + trailing (possibly empty) columns
      sA[64 + lane][(wv * 16 + c) ^ fsw] = a * idg;
      a = 0.f;
      if (++c >= 16) break;
      idg = __shfl(invv, c);
    }
  }
  __syncthreads();

  float acc[4][8];
  #pragma unroll
  for (int i = 0; i < 4; ++i)
    #pragma unroll
    for (int j = 0; j < 8; ++j) acc[i][j] = 0.f;

  #pragma unroll 1
  for (int k0 = 0; k0 < 128; k0 += 32) {
    const float* Wsrc = (k0 < 64) ? (Ws + (size_t)k0 * 128)
                                  : (Wn + (size_t)(k0 - 64) * 128);
    #pragma unroll
    for (int j = 0; j < 4; ++j) {
      int idx = t * 4 + j * 1024;
      int kk = idx >> 7, cix = idx & 127;
      *(float4*)&sW[kk][cix] = *(const float4*)(Wsrc + (size_t)kk * 128 + cix);
    }
    __syncthreads();
    #pragma unroll
    for (int kk = 0; kk < 32; ++kk) {
      const int f = (kk >> 3) & 3;    // compile-time un-permute of the swizzled float4
      float w8[8];
      float4 ar = *(const float4*)&sA[k0 + kk][tr * 4];
      float ax[4] = {ar.x, ar.y, ar.z, ar.w};
      *(float4*)&w8[0] = *(const float4*)&sW[kk][tc * 8];
      *(float4*)&w8[4] = *(const float4*)&sW[kk][tc * 8 + 4];
      #pragma unroll
      for (int i = 0; i < 4; ++i)
        #pragma unroll
        for (int j = 0; j < 8; ++j)
          acc[i][j] = fmaf(ax[i ^ f], w8[j], acc[i][j]);
    }
    __syncthreads();
  }

  #pragma unroll
  for (int i = 0; i < 4; ++i) {
    int seg = seg0 + tr * 4 + i;
    unsigned int pk[4];
    #pragma unroll
    for (int q = 0; q < 4; ++q)
      pk[q] = f2bf(acc[i][2 * q]) | (f2bf(acc[i][2 * q + 1]) << 16);
    uint4 st = {pk[0], pk[1], pk[2], pk[3]};
    *(uint4*)(BUF + (size_t)seg * 128 + tc * 8) = st;
  }
}

// ---------------- gather-GEMM (bf16 src rows, K=128, relu-on-read): ----------------
// OUT[seg] (+)= [sum_{j in seg} w_j * relu(SRC[ent[j]])] @ W     (32 segs/block)
__global__ __launch_bounds__(256)
void k_gg2(int nseg, const int* __restrict__ rp, const int* __restrict__ ent,
           const float* __restrict__ entw, int segscale,
           const unsigned short* __restrict__ SRC, const float* __restrict__ W,
           float* __restrict__ OUT, int beta)
{
  __shared__ float sA[128][36];   // 18432 B
  __shared__ float sW[32][132];   // 16896 B -> 35328, 4 blocks/CU
  const int t = threadIdx.x, wv = t >> 6, lane = t & 63;
  const int tr = t >> 4, tc = t & 15;
  const int seg0 = blockIdx.x * 32;
  const int segbase = seg0 + wv * 8;
  int idxl = segbase + lane;
  int rpv = (lane <= 8 && idxl <= nseg) ? rp[idxl] : 0;

  #pragma unroll 1
  for (int i = 0; i < 8; ++i) {
    int col = wv * 8 + i;
    int seg = seg0 + col;
    float a0 = 0.f, a1 = 0.f;
    if (seg < nseg) {
      int p0 = __shfl(rpv, i), p1 = __shfl(rpv, i + 1);
      int j = p0;
      for (; j + 3 < p1; j += 4) {
        int s0 = ent[j], s1 = ent[j + 1], s2 = ent[j + 2], s3 = ent[j + 3];
        float w0 = entw ? entw[j] : 1.f,     w1 = entw ? entw[j + 1] : 1.f;
        float w2 = entw ? entw[j + 2] : 1.f, w3 = entw ? entw[j + 3] : 1.f;
        unsigned int u0 = *(const unsigned int*)(SRC + (size_t)s0 * 128 + 2 * lane);
        unsigned int u1 = *(const unsigned int*)(SRC + (size_t)s1 * 128 + 2 * lane);
        unsigned int u2 = *(const unsigned int*)(SRC + (size_t)s2 * 128 + 2 * lane);
        unsigned int u3 = *(const unsigned int*)(SRC + (size_t)s3 * 128 + 2 * lane);
        a0 = fmaf(w0, fmaxf(bf2f(u0 & 0xffffu), 0.f), a0);
        a1 = fmaf(w0, fmaxf(bf2f(u0 >> 16),     0.f), a1);
        a0 = fmaf(w1, fmaxf(bf2f(u1 & 0xffffu), 0.f), a0);
        a1 = fmaf(w1, fmaxf(bf2f(u1 >> 16),     0.f), a1);
        a0 = fmaf(w2, fmaxf(bf2f(u2 & 0xffffu), 0.f), a0);
        a1 = fmaf(w2, fmaxf(bf2f(u2 >> 16),     0.f), a1);
        a0 = fmaf(w3, fmaxf(bf2f(u3 & 0xffffu), 0.f), a0);
        a1 = fmaf(w3, fmaxf(bf2f(u3 >> 16),     0.f), a1);
      }
      for (; j < p1; ++j) {
        int s0 = ent[j];
        float w0 = entw ? entw[j] : 1.f;
        unsigned int u0 = *(const unsigned int*)(SRC + (size_t)s0 * 128 + 2 * lane);
        a0 = fmaf(w0, fmaxf(bf2f(u0 & 0xffffu), 0.f), a0);
        a1 = fmaf(w0, fmaxf(bf2f(u0 >> 16),     0.f), a1);
      }
      if (segscale) {
        float sc = 1.f / fmaxf((float)(p1 - p0), 1.f);
        a0 *= sc; a1 *= sc;
      }
    }
    sA[2 * lane][col]     = a0;
    sA[2 * lane + 1][col] = a1;
  }
  __syncthreads();

  float acc[2][8];
  #pragma unroll
  for (int i = 0; i < 2; ++i)
    #pragma unroll
    for (int j = 0; j < 8; ++j) acc[i][j] = 0.f;

  #pragma unroll 1
  for (int k0 = 0; k0 < 128; k0 += 32) {
    #pragma unroll
    for (int j = 0; j < 4; ++j) {
      int idx = t * 4 + j * 1024;
      int kk = idx >> 7, c = idx & 127;
      *(float4*)&sW[kk][c] = *(const float4*)(W + (size_t)(k0 + kk) * 128 + c);
    }
    __syncthreads();
    #pragma unroll
    for (int kk = 0; kk < 32; ++kk) {
      float a2[2], w8[8];
      *(float2*)&a2[0] = *(const float2*)&sA[k0 + kk][tr * 2];
      *(float4*)&w8[0] = *(const float4*)&sW[kk][tc * 8];
      *(float4*)&w8[4] = *(const float4*)&sW[kk][tc * 8 + 4];
      #pragma unroll
      for (int i = 0; i < 2; ++i)
        #pragma unroll
        for (int j = 0; j < 8; ++j)
          acc[i][j] = fmaf(a2[i], w8[j], acc[i][j]);
    }
    __syncthreads();
  }

  #pragma unroll
  for (int i = 0; i < 2; ++i) {
    int seg = seg0 + tr * 2 + i;
    if (seg >= nseg) continue;
    float o[8];
    #pragma unroll
    for (int j = 0; j < 8; ++j) o[j] = acc[i][j];
    float* p = OUT + (size_t)seg * 128 + tc * 8;
    if (beta) {
      float4 c0 = *(const float4*)p, c1 = *(const float4*)(p + 4);
      o[0] += c0.x; o[1] += c0.y; o[2] += c0.z; o[3] += c0.w;
      o[4] += c1.x; o[5] += c1.y; o[6] += c1.z; o[7] += c1.w;
    }
    *(float4*)p       = *(const float4*)&o[0];
    *(float4*)(p + 4) = *(const float4*)&o[4];
  }
}

// ---------------- gather segment-mean (128-wide), O[seg] += mean ----------------
__global__ __launch_bounds__(256)
void k_gsum(const int* __restrict__ rp, const int* __restrict__ ent,
            const float* __restrict__ SRC, float* __restrict__ O, int nseg)
{
  int wv = threadIdx.x >> 6, lane = threadIdx.x & 63;
  int seg = blockIdx.x * 4 + wv;
  if (seg >= nseg) return;
  int p0 = rp[seg], p1 = rp[seg + 1];
  if (p0 >= p1) return;
  float a0 = 0.f, a1 = 0.f;
  int j = p0;
  for (; j + 3 < p1; j += 4) {
    int s0 = ent[j], s1 = ent[j + 1], s2 = ent[j + 2], s3 = ent[j + 3];
    float2 v0 = ((const float2*)(SRC + (size_t)s0 * 128))[lane];
    float2 v1 = ((const float2*)(SRC + (size_t)s1 * 128))[lane];
    float2 v2 = ((const float2*)(SRC + (size_t)s2 * 128))[lane];
    float2 v3 = ((const float2*)(SRC + (size_t)s3 * 128))[lane];
    a0 += (v0.x + v1.x) + (v2.x + v3.x);
    a1 += (v0.y + v1.y) + (v2.y + v3.y);
  }
  for (; j < p1; ++j) {
    float2 v0 = ((const float2*)(SRC + (size_t)ent[j] * 128))[lane];
    a0 += v0.x; a1 += v0.y;
  }
  float sc = 1.f / fmaxf((float)(p1 - p0), 1.f);
  float2* orow = (float2*)(O + (size_t)seg * 128);
  float2 cur = orow[lane];
  cur.x += a0 * sc; cur.y += a1 * sc;
  orow[lane] = cur;
}

// ---------------- fused attention: online softmax + PV, one wave per node ----------------
__global__ __launch_bounds__(256)
void k_attn(const int* __restrict__ rp, const int* __restrict__ ent,
            const float* __restrict__ q, const float* __restrict__ kb,
            const float* __restrict__ vb, float* __restrict__ o, int nseg)
{
  int wv = threadIdx.x >> 6, lane = threadIdx.x & 63;
  int seg = blockIdx.x * 4 + wv;
  if (seg >= nseg) return;
  int p0 = rp[seg], p1 = rp[seg + 1];
  if (p0 >= p1) return;
  float2 q2 = ((const float2*)(q + (size_t)seg * 128))[lane];
  float m = -1e30f, l = 0.f, o0 = 0.f, o1 = 0.f;
  for (int j = p0; j < p1; ++j) {
    int s = ent[j];
    float2 k2 = ((const float2*)(kb + (size_t)s * 128))[lane];
    float d = fmaf(q2.x, k2.x, q2.y * k2.y);
    #pragma unroll
    for (int off = 1; off < 64; off <<= 1) d += __shfl_xor(d, off);
    float sc = d * 0.088388347648318447f;          // 1/sqrt(128)
    sc = sc > 0.f ? sc : 0.2f * sc;                // leaky 0.2
    float mn = fmaxf(m, sc);
    float scale = expf(m - mn);
    float e = expf(sc - mn);
    float2 v2 = ((const float2*)(vb + (size_t)s * 128))[lane];
    l  = l * scale + e;
    o0 = o0 * scale + e * v2.x;
    o1 = o1 * scale + e * v2.y;
    m = mn;
  }
  float inv = 1.f / fmaxf(l, 1e-9f);
  float2* orow = (float2*)(o + (size_t)seg * 128);
  float2 cur = orow[lane];
  cur.x += o0 * inv; cur.y += o1 * inv;
  orow[lane] = cur;
}

// ---------------- classifier + log_softmax ----------------
__global__ __launch_bounds__(256)
void k_out(const float* __restrict__ attn, const float* __restrict__ Wout,
           float* __restrict__ out, int n) {
  __shared__ float sW[128 * 64];
  for (int i = threadIdx.x; i < 128 * 64; i += 256) sW[i] = Wout[i];
  __syncthreads();
  int wave = threadIdx.x >> 6, lane = threadIdx.x & 63;
  int row = blockIdx.x * 4 + wave;
  if (row >= n) return;
  const float* a = attn + (size_t)row * 128;
  float z = 0.f;
  #pragma unroll 8
  for (int k = 0; k < 128; ++k) z = fmaf(a[k], sW[k * 64 + lane], z);
  float mx = z;
  #pragma unroll
  for (int off = 32; off; off >>= 1) mx = fmaxf(mx, __shfl_xor(mx, off));
  float ee = expf(z - mx);
  float ss = ee;
  #pragma unroll
  for (int off = 32; off; off >>= 1) ss += __shfl_xor(ss, off);
  out[(size_t)row * 64 + lane] = z - mx - logf(ss);
}

extern "C" void kernel_launch(void* const* d_in, const int* in_sizes, int n_in,
                              void* d_out, int out_size, void* d_ws, size_t ws_size,
                              hipStream_t stream) {
  (void)in_sizes; (void)n_in; (void)out_size;
  const float* x        = (const float*)d_in[0];
  const float* et       = (const float*)d_in[1];
  const int*   H0       = (const int*)d_in[2];
  const int*   H1       = H0 + Ee;
  const int*   src      = (const int*)d_in[3];
  const int*   dst      = src + Ee;
  const int*   src_lg   = (const int*)d_in[4];
  const int*   dst_lg   = src_lg + LGEe;
  const float* W_tsa1_s = (const float*)d_in[5];
  const float* W_tsa1_n = (const float*)d_in[6];
  const float* W_tsa2_s = (const float*)d_in[7];
  const float* W_tsa2_n = (const float*)d_in[8];
  const float* W_etn    = (const float*)d_in[9];
  const float* W_eg_lin = (const float*)d_in[10];
  const float* W_ea_s   = (const float*)d_in[11];
  const float* W_ea_n   = (const float*)d_in[12];
  const float* W_an1_s  = (const float*)d_in[13];
  const float* W_an1_n  = (const float*)d_in[14];
  const float* W_an2_s  = (const float*)d_in[15];
  const float* W_an2_n  = (const float*)d_in[16];
  const float* Wq       = (const float*)d_in[17];
  const float* Wk       = (const float*)d_in[18];
  const float* Wv       = (const float*)d_in[19];
  const float* W_out    = (const float*)d_in[20];
  float* out = (float*)d_out;

  // ---- workspace carve ----
  char* wp = (char*)d_ws;
  size_t avail = ws_size;
  auto alloc = [&](size_t bytes) -> void* {
    void* r = (void*)wp;
    size_t pad = (bytes + 255) & ~(size_t)255;
    wp += pad; avail = (avail >= pad) ? avail - pad : 0;
    return r;
  };
  const size_t NH = (size_t)Nn * 128;
  unsigned short* BUF = (unsigned short*)alloc((size_t)Ee * 128 * 2); // 204.8MB bf16 h1
  float* agg   = (float*)alloc(NH * 4);
  int* ptrA  = (int*)alloc(((size_t)Ee + 1) * 4);
  int* cntA  = (int*)alloc((size_t)Ee * 4);
  int* entA  = (int*)alloc((size_t)LGEe * 4);
  int* ptrB  = (int*)alloc(((size_t)Nn + 1) * 4);
  int* cntB  = (int*)alloc((size_t)Nn * 4);
  int* entBs = (int*)alloc((size_t)2 * LGEe * 4);
  float* entBw = (float*)alloc((size_t)2 * LGEe * 4);
  int* ptrC  = (int*)alloc(((size_t)Nn + 1) * 4);
  int* cntC  = (int*)alloc((size_t)Nn * 4);
  int* entC  = (int*)alloc((size_t)2 * Ee * 4);
  int* ptrD  = (int*)alloc(((size_t)Nn + 1) * 4);
  int* cntD  = (int*)alloc((size_t)Nn * 4);
  int* entD  = (int*)alloc((size_t)Ee * 4);
  float* rdegN = (float*)alloc((size_t)Nn * 4);
  int* bsum  = (int*)alloc(2048 * 4);
  if (avail == 0 && wp > (char*)d_ws + ws_size) return;  // ws too small: clean fail

  // node-phase f32 arrays overlay BUF (dead after agg is built): 8 x 25.6MB
  float* er  = (float*)BUF + 0 * NH;
  float* ae  = (float*)BUF + 1 * NH;
  float* hn  = (float*)BUF + 2 * NH;
  float* hn2 = (float*)BUF + 3 * NH;
  float* qb  = (float*)BUF + 4 * NH;
  float* kb  = (float*)BUF + 5 * NH;
  float* vb  = (float*)BUF + 6 * NH;
  float* tmp = (float*)BUF + 7 * NH;

  auto cdiv = [](long a, long b) { return (int)((a + b - 1) / b); };
  auto scan = [&](int* cnt, int* ptr, int n, int total) {
    int nb = cdiv(n, 1024);
    k_scan1<<<nb, 256, 0, stream>>>(cnt, ptr, bsum, n);
    k_scan2<<<1, 1024, 0, stream>>>(bsum, nb);
    k_scan3<<<cdiv(n, 256), 256, 0, stream>>>(ptr, bsum, n, total);
  };

  const int gLG = cdiv(LGEe, 256), gEe = cdiv(Ee, 256);

  // ---- CSR A: line-graph by dst_lg (E segments) ----
  hipMemsetAsync(cntA, 0, (size_t)Ee * 4, stream);
  k_count_direct<<<gLG, 256, 0, stream>>>(dst_lg, cntA, LGEe);
  scan(cntA, ptrA, Ee, LGEe);
  hipMemsetAsync(cntA, 0, (size_t)Ee * 4, stream);
  k_fillA<<<gLG, 256, 0, stream>>>(dst_lg, src_lg, ptrA, cntA, entA, LGEe);

  // ---- CSR B: composed H[b][dst_lg[m]] (N segments, 2*LGE entries) ----
  hipMemsetAsync(cntB, 0, (size_t)Nn * 4, stream);
  k_count_comp<<<gLG, 256, 0, stream>>>(H0, dst_lg, cntB, LGEe);
  k_count_comp<<<gLG, 256, 0, stream>>>(H1, dst_lg, cntB, LGEe);
  scan(cntB, ptrB, Nn, 2 * LGEe);
  hipMemsetAsync(cntB, 0, (size_t)Nn * 4, stream);
  k_fillB<<<gLG, 256, 0, stream>>>(H0, dst_lg, src_lg, ptrA, ptrB, cntB, entBs, entBw, LGEe);
  k_fillB<<<gLG, 256, 0, stream>>>(H1, dst_lg, src_lg, ptrA, ptrB, cntB, entBs, entBw, LGEe);

  // ---- CSR C: H incidence (N segments, 2*E entries, value = edge id) ----
  hipMemsetAsync(cntC, 0, (size_t)Nn * 4, stream);
  k_count_direct<<<gEe, 256, 0, stream>>>(H0, cntC, Ee);
  k_count_direct<<<gEe, 256, 0, stream>>>(H1, cntC, Ee);
  scan(cntC, ptrC, Nn, 2 * Ee);
  hipMemsetAsync(cntC, 0, (size_t)Nn * 4, stream);
  k_fillC<<<gEe, 256, 0, stream>>>(H0, ptrC, cntC, entC, Ee);
  k_fillC<<<gEe, 256, 0, stream>>>(H1, ptrC, cntC, entC, Ee);

  // ---- CSR D: raw graph by dst (N segments, E entries, value = src) ----
  hipMemsetAsync(cntD, 0, (size_t)Nn * 4, stream);
  k_count_direct<<<gEe, 256, 0, stream>>>(dst, cntD, Ee);
  scan(cntD, ptrD, Nn, Ee);
  hipMemsetAsync(cntD, 0, (size_t)Nn * 4, stream);
  k_fillD<<<gEe, 256, 0, stream>>>(dst, src, ptrD, cntD, entD, Ee);
  k_rdeg<<<cdiv(Nn, 256), 256, 0, stream>>>(ptrC, rdegN, Nn);

  const int gN128 = cdiv(Nn, 128);      // 391
  const int gN32  = cdiv(Nn, 32);       // 1563
  const int gW    = cdiv(Nn, 4);        // 12500

  // ---- TSA layer 1, fused self+nbr -> BUF (bf16, pre-relu) ----
  k_tsa1<<<Ee / 64, 256, 0, stream>>>(et, ptrA, entA, W_tsa1_s, W_tsa1_n, BUF);

  // ---- TSA layer 2 + EdgeToNode fused at N-scale (agg = P@W2s + Q@W2n) ----
  k_gg2<<<gN32, 256, 0, stream>>>(Nn, ptrC, entC, nullptr, 0, BUF, W_tsa2_s, agg, 0);
  k_gg2<<<gN32, 256, 0, stream>>>(Nn, ptrB, entBs, entBw, 0, BUF, W_tsa2_n, agg, 1);
  k_gemm128<<<gN128, 256, 0, stream>>>(Nn, agg, 128, W_etn, rdegN, 0, 2, tmp);
  k_gemm128<<<gN128, 256, 0, stream>>>(Nn, tmp, 128, W_eg_lin, nullptr, 0, 0, er);

  // ---- edge_aggr SAGE ----
  k_gemm128<<<gN128, 256, 0, stream>>>(Nn, er, 128, W_ea_s, nullptr, 0, 0, ae);
  k_gemm128<<<gN128, 256, 0, stream>>>(Nn, er, 128, W_ea_n, nullptr, 0, 0, tmp);
  k_gsum<<<gW, 256, 0, stream>>>(ptrD, entD, tmp, ae, Nn);

  // ---- attr_node_model (hn kept pre-relu; relu applied on read) ----
  k_gemm128<<<gN128, 256, 0, stream>>>(Nn, x, 256, W_an1_s, nullptr, 0, 0, hn);
  k_gemm128<<<gN128, 256, 0, stream>>>(Nn, x, 256, W_an1_n, nullptr, 0, 0, tmp);
  k_gsum<<<gW, 256, 0, stream>>>(ptrD, entD, tmp, hn, Nn);
  k_gemm128<<<gN128, 256, 0, stream>>>(Nn, hn, 128, W_an2_s, nullptr, 1, 0, hn2);
  k_gemm128<<<gN128, 256, 0, stream>>>(Nn, hn, 128, W_an2_n, nullptr, 1, 0, tmp);
  k_gsum<<<gW, 256, 0, stream>>>(ptrD, entD, tmp, hn2, Nn);

  // ---- MixAttention (fused online softmax; out accumulated into hn2) ----
  k_gemm128<<<gN128, 256, 0, stream>>>(Nn, hn2, 128, Wq, nullptr, 0, 0, qb);
  k_gemm128<<<gN128, 256, 0, stream>>>(Nn, ae, 128, Wk, nullptr, 0, 0, kb);
  k_gemm128<<<gN128, 256, 0, stream>>>(Nn, ae, 128, Wv, nullptr, 0, 0, vb);
  k_attn<<<gW, 256, 0, stream>>>(ptrD, entD, qb, kb, vb, hn2, Nn);

  // ---- classifier + log_softmax ----
  k_out<<<gW, 256, 0, stream>>>(hn2, W_out, out, Nn);
}

// Round 2
// 2999.991 us; speedup vs baseline: 1.2352x; 1.0966x over previous
//
#include <hip/hip_runtime.h>
#include <cstddef>

static constexpr int Nn   = 50000;
static constexpr int Ee   = 800000;
static constexpr int LGEe = 1600000;

typedef __attribute__((ext_vector_type(8))) short bf16x8;
typedef __attribute__((ext_vector_type(4))) float f32x4;

__device__ __forceinline__ float bf2f(unsigned int u16) {
  return __uint_as_float(u16 << 16);
}
__device__ __forceinline__ unsigned int f2bf(float f) {
  unsigned int u = __float_as_uint(f);
  u += 0x7fffu + ((u >> 16) & 1u);   // RNE
  return u >> 16;
}

// ---------------- CSR build kernels ----------------
__global__ __launch_bounds__(256)
void k_count_direct(const int* __restrict__ idx, int* __restrict__ cnt, int n) {
  int i = blockIdx.x * 256 + threadIdx.x;
  if (i < n) atomicAdd(&cnt[idx[i]], 1);
}
__global__ __launch_bounds__(256)
void k_count_comp(const int* __restrict__ Hrow, const int* __restrict__ dlg,
                  int* __restrict__ cnt, int n) {
  int i = blockIdx.x * 256 + threadIdx.x;
  if (i < n) atomicAdd(&cnt[Hrow[dlg[i]]], 1);
}
__global__ __launch_bounds__(256)
void k_scan1(const int* __restrict__ in, int* __restrict__ out,
             int* __restrict__ bsum, int n) {
  __shared__ int sd[256];
  int tid = threadIdx.x;
  int base = blockIdx.x * 1024 + tid * 4;
  int4 v = {0, 0, 0, 0};
  if (base < n) v = *(const int4*)(in + base);   // n % 4 == 0 for all uses
  int s = v.x + v.y + v.z + v.w;
  sd[tid] = s; __syncthreads();
  for (int off = 1; off < 256; off <<= 1) {
    int t_ = (tid >= off) ? sd[tid - off] : 0; __syncthreads();
    sd[tid] += t_; __syncthreads();
  }
  int excl = sd[tid] - s;
  if (base < n) {
    int4 o; o.x = excl; o.y = o.x + v.x; o.z = o.y + v.y; o.w = o.z + v.z;
    *(int4*)(out + base) = o;
  }
  if (tid == 255) bsum[blockIdx.x] = sd[255];
}
__global__ __launch_bounds__(1024)
void k_scan2(int* __restrict__ b, int nb) {
  __shared__ int sd[1024];
  int tid = threadIdx.x;
  int v = (tid < nb) ? b[tid] : 0;
  sd[tid] = v; __syncthreads();
  for (int off = 1; off < 1024; off <<= 1) {
    int t_ = (tid >= off) ? sd[tid - off] : 0; __syncthreads();
    sd[tid] += t_; __syncthreads();
  }
  if (tid < nb) b[tid] = sd[tid] - v;
}
__global__ __launch_bounds__(256)
void k_scan3(int* __restrict__ out, const int* __restrict__ bsum, int n, int total) {
  int i = blockIdx.x * 256 + threadIdx.x;
  if (i < n) out[i] += bsum[i >> 10];
  if (i == 0) out[n] = total;
}
__global__ __launch_bounds__(256)
void k_fillA(const int* __restrict__ dlg, const int* __restrict__ slg,
             const int* __restrict__ ptr, int* __restrict__ cur,
             int* __restrict__ ent, int n) {
  int m = blockIdx.x * 256 + threadIdx.x;
  if (m >= n) return;
  int d = dlg[m];
  int pos = ptr[d] + atomicAdd(&cur[d], 1);
  ent[pos] = slg[m];
}
__global__ __launch_bounds__(256)
void k_fillB(const int* __restrict__ Hrow, const int* __restrict__ dlg,
             const int* __restrict__ slg, const int* __restrict__ ptrA,
             const int* __restrict__ ptrB, int* __restrict__ cur,
             int* __restrict__ entS, float* __restrict__ entW, int n) {
  int m = blockIdx.x * 256 + threadIdx.x;
  if (m >= n) return;
  int d = dlg[m];
  int seg = Hrow[d];
  int pos = ptrB[seg] + atomicAdd(&cur[seg], 1);
  entS[pos] = slg[m];
  int la = ptrA[d + 1] - ptrA[d];
  entW[pos] = 1.0f / (float)max(la, 1);
}
__global__ __launch_bounds__(256)
void k_fillC(const int* __restrict__ Hrow, const int* __restrict__ ptr,
             int* __restrict__ cur, int* __restrict__ ent, int n) {
  int e = blockIdx.x * 256 + threadIdx.x;
  if (e >= n) return;
  int seg = Hrow[e];
  int pos = ptr[seg] + atomicAdd(&cur[seg], 1);
  ent[pos] = e;
}
__global__ __launch_bounds__(256)
void k_fillD(const int* __restrict__ dstA, const int* __restrict__ srcA,
             const int* __restrict__ ptr, int* __restrict__ cur,
             int* __restrict__ ent, int n) {
  int e = blockIdx.x * 256 + threadIdx.x;
  if (e >= n) return;
  int seg = dstA[e];
  int pos = ptr[seg] + atomicAdd(&cur[seg], 1);
  ent[pos] = srcA[e];
}
__global__ __launch_bounds__(256)
void k_rdeg(const int* __restrict__ ptr, float* __restrict__ r, int n) {
  int i = blockIdx.x * 256 + threadIdx.x;
  if (i < n) r[i] = 1.0f / fmaxf((float)(ptr[i + 1] - ptr[i]), 1.0f);
}

// ---------------- dense GEMM: C[Mx128] = act( rowmul(reluA(A)) @ W ) ----------------
// Register tile split 4+4 (tr*4 / 64+tr*4, tc*4 / 64+tc*4): 2-way LDS aliasing = free.
__global__ __launch_bounds__(256)
void k_gemm128(int M, const float* __restrict__ A, int K,
               const float* __restrict__ W, const float* __restrict__ dgA,
               int reluA, int act, float* __restrict__ C)
{
  __shared__ float sA[32][132];
  __shared__ float sW[32][132];
  const int t = threadIdx.x, tr = t >> 4, tc = t & 15;
  const int row0 = blockIdx.x * 128;
  float acc[8][8];
  #pragma unroll
  for (int i = 0; i < 8; ++i)
    #pragma unroll
    for (int j = 0; j < 8; ++j) acc[i][j] = 0.f;

  #pragma unroll 1
  for (int k0 = 0; k0 < K; k0 += 32) {
    __syncthreads();
    #pragma unroll
    for (int j = 0; j < 4; ++j) {
      int idx = t * 4 + j * 1024;
      int r = idx >> 5, kk = idx & 31;
      int gr = row0 + r; if (gr > M - 1) gr = M - 1;
      float4 va = *(const float4*)(A + (size_t)gr * K + k0 + kk);
      if (reluA) {
        va.x = fmaxf(va.x, 0.f); va.y = fmaxf(va.y, 0.f);
        va.z = fmaxf(va.z, 0.f); va.w = fmaxf(va.w, 0.f);
      }
      if (dgA) {
        float sc = dgA[gr];
        va.x *= sc; va.y *= sc; va.z *= sc; va.w *= sc;
      }
      sA[kk + 0][r] = va.x; sA[kk + 1][r] = va.y;
      sA[kk + 2][r] = va.z; sA[kk + 3][r] = va.w;
    }
    #pragma unroll
    for (int j = 0; j < 4; ++j) {
      int idx = t * 4 + j * 1024;
      int kk = idx >> 7, c = idx & 127;
      *(float4*)&sW[kk][c] = *(const float4*)(W + (size_t)(k0 + kk) * 128 + c);
    }
    __syncthreads();
    #pragma unroll
    for (int kk = 0; kk < 32; ++kk) {
      float a[8], w[8];
      *(float4*)&a[0] = *(const float4*)&sA[kk][tr * 4];
      *(float4*)&a[4] = *(const float4*)&sA[kk][64 + tr * 4];
      *(float4*)&w[0] = *(const float4*)&sW[kk][tc * 4];
      *(float4*)&w[4] = *(const float4*)&sW[kk][64 + tc * 4];
      #pragma unroll
      for (int i = 0; i < 8; ++i)
        #pragma unroll
        for (int j = 0; j < 8; ++j)
          acc[i][j] = fmaf(a[i], w[j], acc[i][j]);
    }
  }
  #pragma unroll 1
  for (int i = 0; i < 8; ++i) {
    int gr = row0 + (i & 4) * 16 + tr * 4 + (i & 3);
    if (gr >= M) continue;
    float o[8];
    #pragma unroll
    for (int j = 0; j < 8; ++j) {
      float vv = acc[i][j];
      if (act == 1)      vv = fmaxf(vv, 0.f);
      else if (act == 2) vv = vv > 0.f ? vv : vv * 0.2f;
      o[j] = vv;
    }
    float* p = C + (size_t)gr * 128;
    *(float4*)(p + tc * 4)      = *(const float4*)&o[0];
    *(float4*)(p + 64 + tc * 4) = *(const float4*)&o[4];
  }
}

// ---------------- fused TSA1 (split-bf16 MFMA): ----------------
// BUF[e] = bf16( et[e]@Ws + mean_{s in A(e)} et[s] @ Wn ), 64 segs/block.
// A (64x128 = [direct 64k | gathered 64k]) built in LDS as hi/lo bf16 with
// byte^((seg&7)<<4) swizzle; W frags loaded per-lane from global (L2-hot)
// and split hi/lo in regs; 96 mfma_f32_16x16x32_bf16 per wave, no sW, no
// K-loop barriers. Epilogue via f32 LDS stage for coalesced uint4 stores.
__global__ __launch_bounds__(256)
void k_tsa1(const float* __restrict__ et,
            const int* __restrict__ rp, const int* __restrict__ ent,
            const float* __restrict__ Ws, const float* __restrict__ Wn,
            unsigned short* __restrict__ BUF)
{
  __shared__ __align__(16) unsigned char smem[34816];
  unsigned short* sAh = (unsigned short*)smem;            // [64][128] bf16 hi
  unsigned short* sAl = (unsigned short*)(smem + 16384);  // [64][128] bf16 lo
  int*   sEnt  = (int*)(smem + 32768);                    // 512 ints
  float* stage = (float*)smem;                            // [64][132] f32 (epilogue)

  const int t = threadIdx.x, wv = t >> 6, lane = t & 63;
  const int tr = t >> 4, tc = t & 15;
  const int nrow = lane & 15, kg = lane >> 4;
  const int seg0 = blockIdx.x * 64;
  const int segbase = seg0 + wv * 16;

  // lanes 0..16 hold row pointers of this wave's 16 segments
  int rpv = (lane <= 16) ? rp[segbase + lane] : 0;
  int nxtv = __shfl(rpv, (lane + 1) & 63);
  float invv = 1.f / fmaxf((float)(nxtv - rpv), 1.f);   // valid lanes 0..15

  // cache block's contiguous ent slice (coalesced); >512 falls back to global
  const int base = rp[seg0];
  const int cnt  = rp[seg0 + 64] - base;
  const int lim  = cnt < 512 ? cnt : 512;
  for (int i = t; i < lim; i += 256) sEnt[i] = ent[base + i];

  // direct half (k = lane): coalesced loads, split hi/lo, swizzled b16 writes
  {
    float dv[16];
    #pragma unroll
    for (int i = 0; i < 16; ++i)
      dv[i] = et[(size_t)(segbase + i) * 64 + lane];
    #pragma unroll
    for (int i = 0; i < 16; ++i) {
      int ss = wv * 16 + i;
      unsigned int hi = f2bf(dv[i]);
      float lo = dv[i] - bf2f(hi);
      int idx = ss * 128 + (lane ^ ((ss & 7) << 3));
      sAh[idx] = (unsigned short)hi;
      sAl[idx] = (unsigned short)f2bf(lo);
    }
  }

  // B fragments from global (W is 128KB, L2-resident): lane l supplies
  // B[k = kg*8+j][n = ntile*16 + nrow] for its wave's 2 n-tiles x 4 k-chunks.
  bf16x8 Bh[2][4], Bl[2][4];
  #pragma unroll
  for (int np = 0; np < 2; ++np) {
    int n = (wv * 2 + np) * 16 + nrow;
    #pragma unroll
    for (int kc = 0; kc < 4; ++kc) {
      const float* Wp = (kc < 2) ? Ws : Wn;
      int kr0 = (kc & 1) * 32 + kg * 8;
      #pragma unroll
      for (int j = 0; j < 8; ++j) {
        float w = Wp[(size_t)(kr0 + j) * 128 + n];
        unsigned int hi = f2bf(w);
        float lo = w - bf2f(hi);
        Bh[np][kc][j] = (short)(unsigned short)hi;
        Bl[np][kc][j] = (short)(unsigned short)f2bf(lo);
      }
    }
  }
  __syncthreads();   // sEnt ready

  // gathered half (k = 64+lane): flatten over entries, 8 row-loads in flight
  {
    int q0 = __shfl(rpv, 0);
    int q1 = __shfl(rpv, 16);
    int c = 0;
    int b_next = __shfl(rpv, 1);
    float idg = __shfl(invv, 0);
    float a = 0.f;
    #pragma unroll 1
    for (int j = q0; j < q1; j += 8) {
      float x[8];
      #pragma unroll
      for (int u = 0; u < 8; ++u) {
        int jj = j + u; jj = jj < q1 ? jj : q1 - 1;
        int ix = jj - base;
        int s = (ix < 512) ? sEnt[ix] : ent[jj];
        x[u] = et[(size_t)s * 64 + lane];
      }
      #pragma unroll
      for (int u = 0; u < 8; ++u) {
        int jj = j + u;
        if (jj >= q1) break;
        while (jj >= b_next) {        // column c complete -> flush
          float v = a * idg;
          int ss = wv * 16 + c;
          unsigned int hi = f2bf(v);
          float lo = v - bf2f(hi);
          int idx = ss * 128 + ((64 + lane) ^ ((ss & 7) << 3));
          sAh[idx] = (unsigned short)hi;
          sAl[idx] = (unsigned short)f2bf(lo);
          a = 0.f;
          ++c;
          b_next = __shfl(rpv, c + 1);
          idg = __shfl(invv, c);
        }
        a += x[u];
      }
    }
    #pragma unroll 1
    for (;;) {                        // flush current + trailing columns
      float v = a * idg;
      int ss = wv * 16 + c;
      unsigned int hi = f2bf(v);
      float lo = v - bf2f(hi);
      int idx = ss * 128 + ((64 + lane) ^ ((ss & 7) << 3));
      sAh[idx] = (unsigned short)hi;
      sAl[idx] = (unsigned short)f2bf(lo);
      a = 0.f;
      if (++c >= 16) break;
      idg = __shfl(invv, c);
    }
  }
  __syncthreads();

  // MFMA: out[64 seg][128 feat], split product Ah*Bh + Al*Bh + Ah*Bl
  f32x4 acc[4][2];
  #pragma unroll
  for (int m = 0; m < 4; ++m)
    #pragma unroll
    for (int np = 0; np < 2; ++np)
      acc[m][np] = (f32x4){0.f, 0.f, 0.f, 0.f};

  #pragma unroll
  for (int kc = 0; kc < 4; ++kc) {
    #pragma unroll
    for (int m = 0; m < 4; ++m) {
      int ss = m * 16 + nrow;
      int kbase = kc * 32 + kg * 8;
      int idx = ss * 128 + (kbase ^ ((ss & 7) << 3));
      bf16x8 ah = *(const bf16x8*)(sAh + idx);
      bf16x8 al = *(const bf16x8*)(sAl + idx);
      #pragma unroll
      for (int np = 0; np < 2; ++np) {
        acc[m][np] = __builtin_amdgcn_mfma_f32_16x16x32_bf16(ah, Bh[np][kc], acc[m][np], 0, 0, 0);
        acc[m][np] = __builtin_amdgcn_mfma_f32_16x16x32_bf16(al, Bh[np][kc], acc[m][np], 0, 0, 0);
        acc[m][np] = __builtin_amdgcn_mfma_f32_16x16x32_bf16(ah, Bl[np][kc], acc[m][np], 0, 0, 0);
      }
    }
  }

  // epilogue: C/D frag (col=lane&15, row=(lane>>4)*4+r) -> f32 stage -> uint4
  __syncthreads();
  #pragma unroll
  for (int m = 0; m < 4; ++m)
    #pragma unroll
    for (int np = 0; np < 2; ++np)
      #pragma unroll
      for (int r = 0; r < 4; ++r)
        stage[(m * 16 + kg * 4 + r) * 132 + (wv * 2 + np) * 16 + nrow] = acc[m][np][r];
  __syncthreads();
  #pragma unroll
  for (int i = 0; i < 4; ++i) {
    int s = tr * 4 + i;
    const float* sp = stage + s * 132 + tc * 8;
    float4 v0 = *(const float4*)sp;
    float4 v1 = *(const float4*)(sp + 4);
    unsigned int pk[4];
    pk[0] = f2bf(v0.x) | (f2bf(v0.y) << 16);
    pk[1] = f2bf(v0.z) | (f2bf(v0.w) << 16);
    pk[2] = f2bf(v1.x) | (f2bf(v1.y) << 16);
    pk[3] = f2bf(v1.z) | (f2bf(v1.w) << 16);
    uint4 st = {pk[0], pk[1], pk[2], pk[3]};
    *(uint4*)(BUF + (size_t)(seg0 + s) * 128 + tc * 8) = st;
  }
}

// ---------------- gather-GEMM (bf16 src rows, K=128, relu-on-read): ----------------
// OUT[seg] (+)= [sum_{j in seg} w_j * relu(SRC[ent[j]])] @ W     (32 segs/block)
__global__ __launch_bounds__(256)
void k_gg2(int nseg, const int* __restrict__ rp, const int* __restrict__ ent,
           const float* __restrict__ entw, int segscale,
           const unsigned short* __restrict__ SRC, const float* __restrict__ W,
           float* __restrict__ OUT, int beta)
{
  __shared__ float sA[128][34];   // stride 34: write conflicts 16->8-way, reads free
  __shared__ float sW[32][132];
  const int t = threadIdx.x, wv = t >> 6, lane = t & 63;
  const int tr = t >> 4, tc = t & 15;
  const int seg0 = blockIdx.x * 32;
  const int segbase = seg0 + wv * 8;
  int idxl = segbase + lane;
  int rpv = (lane <= 8 && idxl <= nseg) ? rp[idxl] : 0;

  #pragma unroll 1
  for (int i = 0; i < 8; ++i) {
    int col = wv * 8 + i;
    int seg = seg0 + col;
    float a0 = 0.f, a1 = 0.f;
    if (seg < nseg) {
      int p0 = __shfl(rpv, i), p1 = __shfl(rpv, i + 1);
      int j = p0;
      for (; j + 3 < p1; j += 4) {
        int s0 = ent[j], s1 = ent[j + 1], s2 = ent[j + 2], s3 = ent[j + 3];
        float w0 = entw ? entw[j] : 1.f,     w1 = entw ? entw[j + 1] : 1.f;
        float w2 = entw ? entw[j + 2] : 1.f, w3 = entw ? entw[j + 3] : 1.f;
        unsigned int u0 = *(const unsigned int*)(SRC + (size_t)s0 * 128 + 2 * lane);
        unsigned int u1 = *(const unsigned int*)(SRC + (size_t)s1 * 128 + 2 * lane);
        unsigned int u2 = *(const unsigned int*)(SRC + (size_t)s2 * 128 + 2 * lane);
        unsigned int u3 = *(const unsigned int*)(SRC + (size_t)s3 * 128 + 2 * lane);
        a0 = fmaf(w0, fmaxf(bf2f(u0 & 0xffffu), 0.f), a0);
        a1 = fmaf(w0, fmaxf(bf2f(u0 >> 16),     0.f), a1);
        a0 = fmaf(w1, fmaxf(bf2f(u1 & 0xffffu), 0.f), a0);
        a1 = fmaf(w1, fmaxf(bf2f(u1 >> 16),     0.f), a1);
        a0 = fmaf(w2, fmaxf(bf2f(u2 & 0xffffu), 0.f), a0);
        a1 = fmaf(w2, fmaxf(bf2f(u2 >> 16),     0.f), a1);
        a0 = fmaf(w3, fmaxf(bf2f(u3 & 0xffffu), 0.f), a0);
        a1 = fmaf(w3, fmaxf(bf2f(u3 >> 16),     0.f), a1);
      }
      for (; j < p1; ++j) {
        int s0 = ent[j];
        float w0 = entw ? entw[j] : 1.f;
        unsigned int u0 = *(const unsigned int*)(SRC + (size_t)s0 * 128 + 2 * lane);
        a0 = fmaf(w0, fmaxf(bf2f(u0 & 0xffffu), 0.f), a0);
        a1 = fmaf(w0, fmaxf(bf2f(u0 >> 16),     0.f), a1);
      }
      if (segscale) {
        float sc = 1.f / fmaxf((float)(p1 - p0), 1.f);
        a0 *= sc; a1 *= sc;
      }
    }
    sA[2 * lane][col]     = a0;
    sA[2 * lane + 1][col] = a1;
  }
  __syncthreads();

  float acc[2][8];
  #pragma unroll
  for (int i = 0; i < 2; ++i)
    #pragma unroll
    for (int j = 0; j < 8; ++j) acc[i][j] = 0.f;

  #pragma unroll 1
  for (int k0 = 0; k0 < 128; k0 += 32) {
    #pragma unroll
    for (int j = 0; j < 4; ++j) {
      int idx = t * 4 + j * 1024;
      int kk = idx >> 7, c = idx & 127;
      *(float4*)&sW[kk][c] = *(const float4*)(W + (size_t)(k0 + kk) * 128 + c);
    }
    __syncthreads();
    #pragma unroll
    for (int kk = 0; kk < 32; ++kk) {
      float a2[2], w8[8];
      *(float2*)&a2[0] = *(const float2*)&sA[k0 + kk][tr * 2];
      *(float4*)&w8[0] = *(const float4*)&sW[kk][tc * 4];
      *(float4*)&w8[4] = *(const float4*)&sW[kk][64 + tc * 4];
      #pragma unroll
      for (int i = 0; i < 2; ++i)
        #pragma unroll
        for (int j = 0; j < 8; ++j)
          acc[i][j] = fmaf(a2[i], w8[j], acc[i][j]);
    }
    __syncthreads();
  }

  #pragma unroll
  for (int i = 0; i < 2; ++i) {
    int seg = seg0 + tr * 2 + i;
    if (seg >= nseg) continue;
    float o[8];
    #pragma unroll
    for (int j = 0; j < 8; ++j) o[j] = acc[i][j];
    float* p = OUT + (size_t)seg * 128;
    if (beta) {
      float4 c0 = *(const float4*)(p + tc * 4), c1 = *(const float4*)(p + 64 + tc * 4);
      o[0] += c0.x; o[1] += c0.y; o[2] += c0.z; o[3] += c0.w;
      o[4] += c1.x; o[5] += c1.y; o[6] += c1.z; o[7] += c1.w;
    }
    *(float4*)(p + tc * 4)      = *(const float4*)&o[0];
    *(float4*)(p + 64 + tc * 4) = *(const float4*)&o[4];
  }
}

// ---------------- gather segment-mean (128-wide), O[seg] += mean ----------------
__global__ __launch_bounds__(256)
void k_gsum(const int* __restrict__ rp, const int* __restrict__ ent,
            const float* __restrict__ SRC, float* __restrict__ O, int nseg)
{
  int wv = threadIdx.x >> 6, lane = threadIdx.x & 63;
  int seg = blockIdx.x * 4 + wv;
  if (seg >= nseg) return;
  int p0 = rp[seg], p1 = rp[seg + 1];
  if (p0 >= p1) return;
  float a0 = 0.f, a1 = 0.f;
  int j = p0;
  for (; j + 3 < p1; j += 4) {
    int s0 = ent[j], s1 = ent[j + 1], s2 = ent[j + 2], s3 = ent[j + 3];
    float2 v0 = ((const float2*)(SRC + (size_t)s0 * 128))[lane];
    float2 v1 = ((const float2*)(SRC + (size_t)s1 * 128))[lane];
    float2 v2 = ((const float2*)(SRC + (size_t)s2 * 128))[lane];
    float2 v3 = ((const float2*)(SRC + (size_t)s3 * 128))[lane];
    a0 += (v0.x + v1.x) + (v2.x + v3.x);
    a1 += (v0.y + v1.y) + (v2.y + v3.y);
  }
  for (; j < p1; ++j) {
    float2 v0 = ((const float2*)(SRC + (size_t)ent[j] * 128))[lane];
    a0 += v0.x; a1 += v0.y;
  }
  float sc = 1.f / fmaxf((float)(p1 - p0), 1.f);
  float2* orow = (float2*)(O + (size_t)seg * 128);
  float2 cur = orow[lane];
  cur.x += a0 * sc; cur.y += a1 * sc;
  orow[lane] = cur;
}

// ---------------- fused attention: online softmax + PV, one wave per node ----------------
__global__ __launch_bounds__(256)
void k_attn(const int* __restrict__ rp, const int* __restrict__ ent,
            const float* __restrict__ q, const float* __restrict__ kb,
            const float* __restrict__ vb, float* __restrict__ o, int nseg)
{
  int wv = threadIdx.x >> 6, lane = threadIdx.x & 63;
  int seg = blockIdx.x * 4 + wv;
  if (seg >= nseg) return;
  int p0 = rp[seg], p1 = rp[seg + 1];
  if (p0 >= p1) return;
  float2 q2 = ((const float2*)(q + (size_t)seg * 128))[lane];
  float m = -1e30f, l = 0.f, o0 = 0.f, o1 = 0.f;
  for (int j = p0; j < p1; ++j) {
    int s = ent[j];
    float2 k2 = ((const float2*)(kb + (size_t)s * 128))[lane];
    float d = fmaf(q2.x, k2.x, q2.y * k2.y);
    #pragma unroll
    for (int off = 1; off < 64; off <<= 1) d += __shfl_xor(d, off);
    float sc = d * 0.088388347648318447f;          // 1/sqrt(128)
    sc = sc > 0.f ? sc : 0.2f * sc;                // leaky 0.2
    float mn = fmaxf(m, sc);
    float scale = expf(m - mn);
    float e = expf(sc - mn);
    float2 v2 = ((const float2*)(vb + (size_t)s * 128))[lane];
    l  = l * scale + e;
    o0 = o0 * scale + e * v2.x;
    o1 = o1 * scale + e * v2.y;
    m = mn;
  }
  float inv = 1.f / fmaxf(l, 1e-9f);
  float2* orow = (float2*)(o + (size_t)seg * 128);
  float2 cur = orow[lane];
  cur.x += o0 * inv; cur.y += o1 * inv;
  orow[lane] = cur;
}

// ---------------- classifier + log_softmax ----------------
__global__ __launch_bounds__(256)
void k_out(const float* __restrict__ attn, const float* __restrict__ Wout,
           float* __restrict__ out, int n) {
  __shared__ float sW[128 * 64];
  for (int i = threadIdx.x; i < 128 * 64; i += 256) sW[i] = Wout[i];
  __syncthreads();
  int wave = threadIdx.x >> 6, lane = threadIdx.x & 63;
  int row = blockIdx.x * 4 + wave;
  if (row >= n) return;
  const float* a = attn + (size_t)row * 128;
  float z = 0.f;
  #pragma unroll 8
  for (int k = 0; k < 128; ++k) z = fmaf(a[k], sW[k * 64 + lane], z);
  float mx = z;
  #pragma unroll
  for (int off = 32; off; off >>= 1) mx = fmaxf(mx, __shfl_xor(mx, off));
  float ee = expf(z - mx);
  float ss = ee;
  #pragma unroll
  for (int off = 32; off; off >>= 1) ss += __shfl_xor(ss, off);
  out[(size_t)row * 64 + lane] = z - mx - logf(ss);
}

extern "C" void kernel_launch(void* const* d_in, const int* in_sizes, int n_in,
                              void* d_out, int out_size, void* d_ws, size_t ws_size,
                              hipStream_t stream) {
  (void)in_sizes; (void)n_in; (void)out_size;
  const float* x        = (const float*)d_in[0];
  const float* et       = (const float*)d_in[1];
  const int*   H0       = (const int*)d_in[2];
  const int*   H1       = H0 + Ee;
  const int*   src      = (const int*)d_in[3];
  const int*   dst      = src + Ee;
  const int*   src_lg   = (const int*)d_in[4];
  const int*   dst_lg   = src_lg + LGEe;
  const float* W_tsa1_s = (const float*)d_in[5];
  const float* W_tsa1_n = (const float*)d_in[6];
  const float* W_tsa2_s = (const float*)d_in[7];
  const float* W_tsa2_n = (const float*)d_in[8];
  const float* W_etn    = (const float*)d_in[9];
  const float* W_eg_lin = (const float*)d_in[10];
  const float* W_ea_s   = (const float*)d_in[11];
  const float* W_ea_n   = (const float*)d_in[12];
  const float* W_an1_s  = (const float*)d_in[13];
  const float* W_an1_n  = (const float*)d_in[14];
  const float* W_an2_s  = (const float*)d_in[15];
  const float* W_an2_n  = (const float*)d_in[16];
  const float* Wq       = (const float*)d_in[17];
  const float* Wk       = (const float*)d_in[18];
  const float* Wv       = (const float*)d_in[19];
  const float* W_out    = (const float*)d_in[20];
  float* out = (float*)d_out;

  // ---- workspace carve ----
  char* wp = (char*)d_ws;
  size_t avail = ws_size;
  auto alloc = [&](size_t bytes) -> void* {
    void* r = (void*)wp;
    size_t pad = (bytes + 255) & ~(size_t)255;
    wp += pad; avail = (avail >= pad) ? avail - pad : 0;
    return r;
  };
  const size_t NH = (size_t)Nn * 128;
  unsigned short* BUF = (unsigned short*)alloc((size_t)Ee * 128 * 2); // 204.8MB bf16 h1
  float* agg   = (float*)alloc(NH * 4);
  int* ptrA  = (int*)alloc(((size_t)Ee + 1) * 4);
  int* cntA  = (int*)alloc((size_t)Ee * 4);
  int* entA  = (int*)alloc((size_t)LGEe * 4);
  int* ptrB  = (int*)alloc(((size_t)Nn + 1) * 4);
  int* cntB  = (int*)alloc((size_t)Nn * 4);
  int* entBs = (int*)alloc((size_t)2 * LGEe * 4);
  float* entBw = (float*)alloc((size_t)2 * LGEe * 4);
  int* ptrC  = (int*)alloc(((size_t)Nn + 1) * 4);
  int* cntC  = (int*)alloc((size_t)Nn * 4);
  int* entC  = (int*)alloc((size_t)2 * Ee * 4);
  int* ptrD  = (int*)alloc(((size_t)Nn + 1) * 4);
  int* cntD  = (int*)alloc((size_t)Nn * 4);
  int* entD  = (int*)alloc((size_t)Ee * 4);
  float* rdegN = (float*)alloc((size_t)Nn * 4);
  int* bsum  = (int*)alloc(2048 * 4);
  if (avail == 0 && wp > (char*)d_ws + ws_size) return;  // ws too small: clean fail

  // node-phase f32 arrays overlay BUF (dead after agg is built): 8 x 25.6MB
  float* er  = (float*)BUF + 0 * NH;
  float* ae  = (float*)BUF + 1 * NH;
  float* hn  = (float*)BUF + 2 * NH;
  float* hn2 = (float*)BUF + 3 * NH;
  float* qb  = (float*)BUF + 4 * NH;
  float* kb  = (float*)BUF + 5 * NH;
  float* vb  = (float*)BUF + 6 * NH;
  float* tmp = (float*)BUF + 7 * NH;

  auto cdiv = [](long a, long b) { return (int)((a + b - 1) / b); };
  auto scan = [&](int* cnt, int* ptr, int n, int total) {
    int nb = cdiv(n, 1024);
    k_scan1<<<nb, 256, 0, stream>>>(cnt, ptr, bsum, n);
    k_scan2<<<1, 1024, 0, stream>>>(bsum, nb);
    k_scan3<<<cdiv(n, 256), 256, 0, stream>>>(ptr, bsum, n, total);
  };

  const int gLG = cdiv(LGEe, 256), gEe = cdiv(Ee, 256);

  // ---- CSR A: line-graph by dst_lg (E segments) ----
  hipMemsetAsync(cntA, 0, (size_t)Ee * 4, stream);
  k_count_direct<<<gLG, 256, 0, stream>>>(dst_lg, cntA, LGEe);
  scan(cntA, ptrA, Ee, LGEe);
  hipMemsetAsync(cntA, 0, (size_t)Ee * 4, stream);
  k_fillA<<<gLG, 256, 0, stream>>>(dst_lg, src_lg, ptrA, cntA, entA, LGEe);

  // ---- CSR B: composed H[b][dst_lg[m]] (N segments, 2*LGE entries) ----
  hipMemsetAsync(cntB, 0, (size_t)Nn * 4, stream);
  k_count_comp<<<gLG, 256, 0, stream>>>(H0, dst_lg, cntB, LGEe);
  k_count_comp<<<gLG, 256, 0, stream>>>(H1, dst_lg, cntB, LGEe);
  scan(cntB, ptrB, Nn, 2 * LGEe);
  hipMemsetAsync(cntB, 0, (size_t)Nn * 4, stream);
  k_fillB<<<gLG, 256, 0, stream>>>(H0, dst_lg, src_lg, ptrA, ptrB, cntB, entBs, entBw, LGEe);
  k_fillB<<<gLG, 256, 0, stream>>>(H1, dst_lg, src_lg, ptrA, ptrB, cntB, entBs, entBw, LGEe);

  // ---- CSR C: H incidence (N segments, 2*E entries, value = edge id) ----
  hipMemsetAsync(cntC, 0, (size_t)Nn * 4, stream);
  k_count_direct<<<gEe, 256, 0, stream>>>(H0, cntC, Ee);
  k_count_direct<<<gEe, 256, 0, stream>>>(H1, cntC, Ee);
  scan(cntC, ptrC, Nn, 2 * Ee);
  hipMemsetAsync(cntC, 0, (size_t)Nn * 4, stream);
  k_fillC<<<gEe, 256, 0, stream>>>(H0, ptrC, cntC, entC, Ee);
  k_fillC<<<gEe, 256, 0, stream>>>(H1, ptrC, cntC, entC, Ee);

  // ---- CSR D: raw graph by dst (N segments, E entries, value = src) ----
  hipMemsetAsync(cntD, 0, (size_t)Nn * 4, stream);
  k_count_direct<<<gEe, 256, 0, stream>>>(dst, cntD, Ee);
  scan(cntD, ptrD, Nn, Ee);
  hipMemsetAsync(cntD, 0, (size_t)Nn * 4, stream);
  k_fillD<<<gEe, 256, 0, stream>>>(dst, src, ptrD, cntD, entD, Ee);
  k_rdeg<<<cdiv(Nn, 256), 256, 0, stream>>>(ptrC, rdegN, Nn);

  const int gN128 = cdiv(Nn, 128);      // 391
  const int gN32  = cdiv(Nn, 32);       // 1563
  const int gW    = cdiv(Nn, 4);        // 12500

  // ---- TSA layer 1, fused self+nbr -> BUF (bf16, pre-relu), split-bf16 MFMA ----
  k_tsa1<<<Ee / 64, 256, 0, stream>>>(et, ptrA, entA, W_tsa1_s, W_tsa1_n, BUF);

  // ---- TSA layer 2 + EdgeToNode fused at N-scale (agg = P@W2s + Q@W2n) ----
  k_gg2<<<gN32, 256, 0, stream>>>(Nn, ptrC, entC, nullptr, 0, BUF, W_tsa2_s, agg, 0);
  k_gg2<<<gN32, 256, 0, stream>>>(Nn, ptrB, entBs, entBw, 0, BUF, W_tsa2_n, agg, 1);
  k_gemm128<<<gN128, 256, 0, stream>>>(Nn, agg, 128, W_etn, rdegN, 0, 2, tmp);
  k_gemm128<<<gN128, 256, 0, stream>>>(Nn, tmp, 128, W_eg_lin, nullptr, 0, 0, er);

  // ---- edge_aggr SAGE ----
  k_gemm128<<<gN128, 256, 0, stream>>>(Nn, er, 128, W_ea_s, nullptr, 0, 0, ae);
  k_gemm128<<<gN128, 256, 0, stream>>>(Nn, er, 128, W_ea_n, nullptr, 0, 0, tmp);
  k_gsum<<<gW, 256, 0, stream>>>(ptrD, entD, tmp, ae, Nn);

  // ---- attr_node_model (hn kept pre-relu; relu applied on read) ----
  k_gemm128<<<gN128, 256, 0, stream>>>(Nn, x, 256, W_an1_s, nullptr, 0, 0, hn);
  k_gemm128<<<gN128, 256, 0, stream>>>(Nn, x, 256, W_an1_n, nullptr, 0, 0, tmp);
  k_gsum<<<gW, 256, 0, stream>>>(ptrD, entD, tmp, hn, Nn);
  k_gemm128<<<gN128, 256, 0, stream>>>(Nn, hn, 128, W_an2_s, nullptr, 1, 0, hn2);
  k_gemm128<<<gN128, 256, 0, stream>>>(Nn, hn, 128, W_an2_n, nullptr, 1, 0, tmp);
  k_gsum<<<gW, 256, 0, stream>>>(ptrD, entD, tmp, hn2, Nn);

  // ---- MixAttention (fused online softmax; out accumulated into hn2) ----
  k_gemm128<<<gN128, 256, 0, stream>>>(Nn, hn2, 128, Wq, nullptr, 0, 0, qb);
  k_gemm128<<<gN128, 256, 0, stream>>>(Nn, ae, 128, Wk, nullptr, 0, 0, kb);
  k_gemm128<<<gN128, 256, 0, stream>>>(Nn, ae, 128, Wv, nullptr, 0, 0, vb);
  k_attn<<<gW, 256, 0, stream>>>(ptrD, entD, qb, kb, vb, hn2, Nn);

  // ---- classifier + log_softmax ----
  k_out<<<gW, 256, 0, stream>>>(hn2, W_out, out, Nn);
}

// Round 3
// 2855.297 us; speedup vs baseline: 1.2978x; 1.0507x over previous
//
#include <hip/hip_runtime.h>
#include <cstddef>

static constexpr int Nn   = 50000;
static constexpr int Ee   = 800000;
static constexpr int LGEe = 1600000;

typedef __attribute__((ext_vector_type(8))) short bf16x8;
typedef __attribute__((ext_vector_type(4))) float f32x4;

__device__ __forceinline__ float bf2f(unsigned int u16) {
  return __uint_as_float(u16 << 16);
}
__device__ __forceinline__ unsigned int f2bf(float f) {
  unsigned int u = __float_as_uint(f);
  u += 0x7fffu + ((u >> 16) & 1u);   // RNE
  return u >> 16;
}

// ---------------- CSR build kernels ----------------
__global__ __launch_bounds__(256)
void k_count_direct(const int* __restrict__ idx, int* __restrict__ cnt, int n) {
  int i = blockIdx.x * 256 + threadIdx.x;
  if (i < n) atomicAdd(&cnt[idx[i]], 1);
}
__global__ __launch_bounds__(256)
void k_count_comp(const int* __restrict__ Hrow, const int* __restrict__ dlg,
                  int* __restrict__ cnt, int n) {
  int i = blockIdx.x * 256 + threadIdx.x;
  if (i < n) atomicAdd(&cnt[Hrow[dlg[i]]], 1);
}
__global__ __launch_bounds__(256)
void k_scan1(const int* __restrict__ in, int* __restrict__ out,
             int* __restrict__ bsum, int n) {
  __shared__ int sd[256];
  int tid = threadIdx.x;
  int base = blockIdx.x * 1024 + tid * 4;
  int4 v = {0, 0, 0, 0};
  if (base < n) v = *(const int4*)(in + base);   // n % 4 == 0 for all uses
  int s = v.x + v.y + v.z + v.w;
  sd[tid] = s; __syncthreads();
  for (int off = 1; off < 256; off <<= 1) {
    int t_ = (tid >= off) ? sd[tid - off] : 0; __syncthreads();
    sd[tid] += t_; __syncthreads();
  }
  int excl = sd[tid] - s;
  if (base < n) {
    int4 o; o.x = excl; o.y = o.x + v.x; o.z = o.y + v.y; o.w = o.z + v.z;
    *(int4*)(out + base) = o;
  }
  if (tid == 255) bsum[blockIdx.x] = sd[255];
}
__global__ __launch_bounds__(1024)
void k_scan2(int* __restrict__ b, int nb) {
  __shared__ int sd[1024];
  int tid = threadIdx.x;
  int v = (tid < nb) ? b[tid] : 0;
  sd[tid] = v; __syncthreads();
  for (int off = 1; off < 1024; off <<= 1) {
    int t_ = (tid >= off) ? sd[tid - off] : 0; __syncthreads();
    sd[tid] += t_; __syncthreads();
  }
  if (tid < nb) b[tid] = sd[tid] - v;
}
__global__ __launch_bounds__(256)
void k_scan3(int* __restrict__ out, const int* __restrict__ bsum, int n, int total) {
  int i = blockIdx.x * 256 + threadIdx.x;
  if (i < n) out[i] += bsum[i >> 10];
  if (i == 0) out[n] = total;
}
__global__ __launch_bounds__(256)
void k_fillA(const int* __restrict__ dlg, const int* __restrict__ slg,
             const int* __restrict__ ptr, int* __restrict__ cur,
             int* __restrict__ ent, int n) {
  int m = blockIdx.x * 256 + threadIdx.x;
  if (m >= n) return;
  int d = dlg[m];
  int pos = ptr[d] + atomicAdd(&cur[d], 1);
  ent[pos] = slg[m];
}
__global__ __launch_bounds__(256)
void k_fillB(const int* __restrict__ Hrow, const int* __restrict__ dlg,
             const int* __restrict__ slg, const int* __restrict__ ptrA,
             const int* __restrict__ ptrB, int* __restrict__ cur,
             int* __restrict__ entS, float* __restrict__ entW, int n) {
  int m = blockIdx.x * 256 + threadIdx.x;
  if (m >= n) return;
  int d = dlg[m];
  int seg = Hrow[d];
  int pos = ptrB[seg] + atomicAdd(&cur[seg], 1);
  entS[pos] = slg[m];
  int la = ptrA[d + 1] - ptrA[d];
  entW[pos] = 1.0f / (float)max(la, 1);
}
__global__ __launch_bounds__(256)
void k_fillC(const int* __restrict__ Hrow, const int* __restrict__ ptr,
             int* __restrict__ cur, int* __restrict__ ent, int n) {
  int e = blockIdx.x * 256 + threadIdx.x;
  if (e >= n) return;
  int seg = Hrow[e];
  int pos = ptr[seg] + atomicAdd(&cur[seg], 1);
  ent[pos] = e;
}
__global__ __launch_bounds__(256)
void k_fillD(const int* __restrict__ dstA, const int* __restrict__ srcA,
             const int* __restrict__ ptr, int* __restrict__ cur,
             int* __restrict__ ent, int n) {
  int e = blockIdx.x * 256 + threadIdx.x;
  if (e >= n) return;
  int seg = dstA[e];
  int pos = ptr[seg] + atomicAdd(&cur[seg], 1);
  ent[pos] = srcA[e];
}
__global__ __launch_bounds__(256)
void k_rdeg(const int* __restrict__ ptr, float* __restrict__ r, int n) {
  int i = blockIdx.x * 256 + threadIdx.x;
  if (i < n) r[i] = 1.0f / fmaxf((float)(ptr[i + 1] - ptr[i]), 1.0f);
}

// ---------------- dense GEMM: C[Mx128] = act( rowmul(reluA(A)) @ W ) ----------------
// Register tile split 4+4 (tr*4 / 64+tr*4, tc*4 / 64+tc*4): 2-way LDS aliasing = free.
__global__ __launch_bounds__(256)
void k_gemm128(int M, const float* __restrict__ A, int K,
               const float* __restrict__ W, const float* __restrict__ dgA,
               int reluA, int act, float* __restrict__ C)
{
  __shared__ float sA[32][132];
  __shared__ float sW[32][132];
  const int t = threadIdx.x, tr = t >> 4, tc = t & 15;
  const int row0 = blockIdx.x * 128;
  float acc[8][8];
  #pragma unroll
  for (int i = 0; i < 8; ++i)
    #pragma unroll
    for (int j = 0; j < 8; ++j) acc[i][j] = 0.f;

  #pragma unroll 1
  for (int k0 = 0; k0 < K; k0 += 32) {
    __syncthreads();
    #pragma unroll
    for (int j = 0; j < 4; ++j) {
      int idx = t * 4 + j * 1024;
      int r = idx >> 5, kk = idx & 31;
      int gr = row0 + r; if (gr > M - 1) gr = M - 1;
      float4 va = *(const float4*)(A + (size_t)gr * K + k0 + kk);
      if (reluA) {
        va.x = fmaxf(va.x, 0.f); va.y = fmaxf(va.y, 0.f);
        va.z = fmaxf(va.z, 0.f); va.w = fmaxf(va.w, 0.f);
      }
      if (dgA) {
        float sc = dgA[gr];
        va.x *= sc; va.y *= sc; va.z *= sc; va.w *= sc;
      }
      sA[kk + 0][r] = va.x; sA[kk + 1][r] = va.y;
      sA[kk + 2][r] = va.z; sA[kk + 3][r] = va.w;
    }
    #pragma unroll
    for (int j = 0; j < 4; ++j) {
      int idx = t * 4 + j * 1024;
      int kk = idx >> 7, c = idx & 127;
      *(float4*)&sW[kk][c] = *(const float4*)(W + (size_t)(k0 + kk) * 128 + c);
    }
    __syncthreads();
    #pragma unroll
    for (int kk = 0; kk < 32; ++kk) {
      float a[8], w[8];
      *(float4*)&a[0] = *(const float4*)&sA[kk][tr * 4];
      *(float4*)&a[4] = *(const float4*)&sA[kk][64 + tr * 4];
      *(float4*)&w[0] = *(const float4*)&sW[kk][tc * 4];
      *(float4*)&w[4] = *(const float4*)&sW[kk][64 + tc * 4];
      #pragma unroll
      for (int i = 0; i < 8; ++i)
        #pragma unroll
        for (int j = 0; j < 8; ++j)
          acc[i][j] = fmaf(a[i], w[j], acc[i][j]);
    }
  }
  #pragma unroll 1
  for (int i = 0; i < 8; ++i) {
    int gr = row0 + (i & 4) * 16 + tr * 4 + (i & 3);
    if (gr >= M) continue;
    float o[8];
    #pragma unroll
    for (int j = 0; j < 8; ++j) {
      float vv = acc[i][j];
      if (act == 1)      vv = fmaxf(vv, 0.f);
      else if (act == 2) vv = vv > 0.f ? vv : vv * 0.2f;
      o[j] = vv;
    }
    float* p = C + (size_t)gr * 128;
    *(float4*)(p + tc * 4)      = *(const float4*)&o[0];
    *(float4*)(p + 64 + tc * 4) = *(const float4*)&o[4];
  }
}

// ---------------- fused TSA1 (split-bf16 MFMA): ----------------
// BUF[e] = bf16( et[e]@Ws + mean_{s in A(e)} et[s] @ Wn ), 64 segs/block.
__global__ __launch_bounds__(256)
void k_tsa1(const float* __restrict__ et,
            const int* __restrict__ rp, const int* __restrict__ ent,
            const float* __restrict__ Ws, const float* __restrict__ Wn,
            unsigned short* __restrict__ BUF)
{
  __shared__ __align__(16) unsigned char smem[34816];
  unsigned short* sAh = (unsigned short*)smem;            // [64][128] bf16 hi
  unsigned short* sAl = (unsigned short*)(smem + 16384);  // [64][128] bf16 lo
  int*   sEnt  = (int*)(smem + 32768);                    // 512 ints
  float* stage = (float*)smem;                            // [64][132] f32 (epilogue)

  const int t = threadIdx.x, wv = t >> 6, lane = t & 63;
  const int tr = t >> 4, tc = t & 15;
  const int nrow = lane & 15, kg = lane >> 4;
  const int seg0 = blockIdx.x * 64;
  const int segbase = seg0 + wv * 16;

  // lanes 0..16 hold row pointers of this wave's 16 segments
  int rpv = (lane <= 16) ? rp[segbase + lane] : 0;
  int nxtv = __shfl(rpv, (lane + 1) & 63);
  float invv = 1.f / fmaxf((float)(nxtv - rpv), 1.f);   // valid lanes 0..15

  // cache block's contiguous ent slice (coalesced); >512 falls back to global
  const int base = rp[seg0];
  const int cnt  = rp[seg0 + 64] - base;
  const int lim  = cnt < 512 ? cnt : 512;
  for (int i = t; i < lim; i += 256) sEnt[i] = ent[base + i];

  // direct half (k = lane): coalesced loads, split hi/lo, swizzled b16 writes
  {
    float dv[16];
    #pragma unroll
    for (int i = 0; i < 16; ++i)
      dv[i] = et[(size_t)(segbase + i) * 64 + lane];
    #pragma unroll
    for (int i = 0; i < 16; ++i) {
      int ss = wv * 16 + i;
      unsigned int hi = f2bf(dv[i]);
      float lo = dv[i] - bf2f(hi);
      int idx = ss * 128 + (lane ^ ((ss & 7) << 3));
      sAh[idx] = (unsigned short)hi;
      sAl[idx] = (unsigned short)f2bf(lo);
    }
  }

  // B fragments from global (W is 128KB, L2-resident): lane l supplies
  // B[k = kg*8+j][n = ntile*16 + nrow] for its wave's 2 n-tiles x 4 k-chunks.
  bf16x8 Bh[2][4], Bl[2][4];
  #pragma unroll
  for (int np = 0; np < 2; ++np) {
    int n = (wv * 2 + np) * 16 + nrow;
    #pragma unroll
    for (int kc = 0; kc < 4; ++kc) {
      const float* Wp = (kc < 2) ? Ws : Wn;
      int kr0 = (kc & 1) * 32 + kg * 8;
      #pragma unroll
      for (int j = 0; j < 8; ++j) {
        float w = Wp[(size_t)(kr0 + j) * 128 + n];
        unsigned int hi = f2bf(w);
        float lo = w - bf2f(hi);
        Bh[np][kc][j] = (short)(unsigned short)hi;
        Bl[np][kc][j] = (short)(unsigned short)f2bf(lo);
      }
    }
  }
  __syncthreads();   // sEnt ready

  // gathered half (k = 64+lane): flatten over entries, 8 row-loads in flight
  {
    int q0 = __shfl(rpv, 0);
    int q1 = __shfl(rpv, 16);
    int c = 0;
    int b_next = __shfl(rpv, 1);
    float idg = __shfl(invv, 0);
    float a = 0.f;
    #pragma unroll 1
    for (int j = q0; j < q1; j += 8) {
      float x[8];
      #pragma unroll
      for (int u = 0; u < 8; ++u) {
        int jj = j + u; jj = jj < q1 ? jj : q1 - 1;
        int ix = jj - base;
        int s = (ix < 512) ? sEnt[ix] : ent[jj];
        x[u] = et[(size_t)s * 64 + lane];
      }
      #pragma unroll
      for (int u = 0; u < 8; ++u) {
        int jj = j + u;
        if (jj >= q1) break;
        while (jj >= b_next) {        // column c complete -> flush
          float v = a * idg;
          int ss = wv * 16 + c;
          unsigned int hi = f2bf(v);
          float lo = v - bf2f(hi);
          int idx = ss * 128 + ((64 + lane) ^ ((ss & 7) << 3));
          sAh[idx] = (unsigned short)hi;
          sAl[idx] = (unsigned short)f2bf(lo);
          a = 0.f;
          ++c;
          b_next = __shfl(rpv, c + 1);
          idg = __shfl(invv, c);
        }
        a += x[u];
      }
    }
    #pragma unroll 1
    for (;;) {                        // flush current + trailing columns
      float v = a * idg;
      int ss = wv * 16 + c;
      unsigned int hi = f2bf(v);
      float lo = v - bf2f(hi);
      int idx = ss * 128 + ((64 + lane) ^ ((ss & 7) << 3));
      sAh[idx] = (unsigned short)hi;
      sAl[idx] = (unsigned short)f2bf(lo);
      a = 0.f;
      if (++c >= 16) break;
      idg = __shfl(invv, c);
    }
  }
  __syncthreads();

  // MFMA: out[64 seg][128 feat], split product Ah*Bh + Al*Bh + Ah*Bl
  f32x4 acc[4][2];
  #pragma unroll
  for (int m = 0; m < 4; ++m)
    #pragma unroll
    for (int np = 0; np < 2; ++np)
      acc[m][np] = (f32x4){0.f, 0.f, 0.f, 0.f};

  #pragma unroll
  for (int kc = 0; kc < 4; ++kc) {
    #pragma unroll
    for (int m = 0; m < 4; ++m) {
      int ss = m * 16 + nrow;
      int kbase = kc * 32 + kg * 8;
      int idx = ss * 128 + (kbase ^ ((ss & 7) << 3));
      bf16x8 ah = *(const bf16x8*)(sAh + idx);
      bf16x8 al = *(const bf16x8*)(sAl + idx);
      #pragma unroll
      for (int np = 0; np < 2; ++np) {
        acc[m][np] = __builtin_amdgcn_mfma_f32_16x16x32_bf16(ah, Bh[np][kc], acc[m][np], 0, 0, 0);
        acc[m][np] = __builtin_amdgcn_mfma_f32_16x16x32_bf16(al, Bh[np][kc], acc[m][np], 0, 0, 0);
        acc[m][np] = __builtin_amdgcn_mfma_f32_16x16x32_bf16(ah, Bl[np][kc], acc[m][np], 0, 0, 0);
      }
    }
  }

  // epilogue: C/D frag (col=lane&15, row=(lane>>4)*4+r) -> f32 stage -> uint4
  __syncthreads();
  #pragma unroll
  for (int m = 0; m < 4; ++m)
    #pragma unroll
    for (int np = 0; np < 2; ++np)
      #pragma unroll
      for (int r = 0; r < 4; ++r)
        stage[(m * 16 + kg * 4 + r) * 132 + (wv * 2 + np) * 16 + nrow] = acc[m][np][r];
  __syncthreads();
  #pragma unroll
  for (int i = 0; i < 4; ++i) {
    int s = tr * 4 + i;
    const float* sp = stage + s * 132 + tc * 8;
    float4 v0 = *(const float4*)sp;
    float4 v1 = *(const float4*)(sp + 4);
    unsigned int pk[4];
    pk[0] = f2bf(v0.x) | (f2bf(v0.y) << 16);
    pk[1] = f2bf(v0.z) | (f2bf(v0.w) << 16);
    pk[2] = f2bf(v1.x) | (f2bf(v1.y) << 16);
    pk[3] = f2bf(v1.z) | (f2bf(v1.w) << 16);
    uint4 st = {pk[0], pk[1], pk[2], pk[3]};
    *(uint4*)(BUF + (size_t)(seg0 + s) * 128 + tc * 8) = st;
  }
}

// ---------------- gather-GEMM (bf16 src rows, K=128, relu-on-read): ----------------
// OUT[seg] (+)= [sum_{j in seg} w_j * relu(SRC[ent[j]])] @ W     (32 segs/block)
// Flattened per-wave entry walk (8 row-loads in flight), LDS ent cache.
__global__ __launch_bounds__(256)
void k_gg2(int nseg, const int* __restrict__ rp, const int* __restrict__ ent,
           const float* __restrict__ entw, int segscale,
           const unsigned short* __restrict__ SRC, const float* __restrict__ W,
           float* __restrict__ OUT, int beta)
{
  __shared__ float sA[128][34];   // 17408 B
  __shared__ float sW[32][132];   // 16896 B
  __shared__ int sEnt[1024];      //  4096 B -> 38400 total, 4 blocks/CU
  const int t = threadIdx.x, wv = t >> 6, lane = t & 63;
  const int tr = t >> 4, tc = t & 15;
  const int seg0 = blockIdx.x * 32;
  const int segbase = seg0 + wv * 8;
  int idxl = segbase + lane;
  int rpv = (lane <= 8 && idxl <= nseg) ? rp[idxl] : 0;
  int nxt = __shfl(rpv, (lane + 1) & 63);
  float invv = 1.f / fmaxf((float)(nxt - rpv), 1.f);   // valid lanes 0..7

  // stage block's contiguous entry slice (coalesced); >1024 falls back to global
  const int base = rp[seg0];
  int endseg = seg0 + 32; if (endseg > nseg) endseg = nseg;
  const int cnt = rp[endseg] - base;
  const int lim = cnt < 1024 ? cnt : 1024;
  for (int i = t; i < lim; i += 256) sEnt[i] = ent[base + i];
  __syncthreads();

  // flattened gather: entries are column-sorted within the wave's range
  {
    int q0 = __shfl(rpv, 0), q1 = __shfl(rpv, 8);
    int c = 0;
    int b_next = __shfl(rpv, 1);
    float a0 = 0.f, a1 = 0.f;
    #pragma unroll 1
    for (int j = q0; j < q1; j += 8) {
      int ids[8];
      unsigned int u[8];
      float w[8];
      #pragma unroll
      for (int uu = 0; uu < 8; ++uu) {
        int jj = j + uu; jj = jj < q1 ? jj : q1 - 1;
        int ix = jj - base;
        ids[uu] = (ix < 1024) ? sEnt[ix] : ent[jj];
      }
      #pragma unroll
      for (int uu = 0; uu < 8; ++uu)
        u[uu] = *(const unsigned int*)(SRC + (size_t)ids[uu] * 128 + 2 * lane);
      if (entw) {
        #pragma unroll
        for (int uu = 0; uu < 8; ++uu) {
          int jj = j + uu; jj = jj < q1 ? jj : q1 - 1;
          w[uu] = entw[jj];
        }
      }
      #pragma unroll
      for (int uu = 0; uu < 8; ++uu) {
        int jj = j + uu;
        if (jj >= q1) break;
        while (jj >= b_next) {        // column c complete -> flush
          float s0 = a0, s1 = a1;
          if (segscale) { float sc = __shfl(invv, c); s0 *= sc; s1 *= sc; }
          int col = wv * 8 + c;
          sA[2 * lane][col]     = s0;
          sA[2 * lane + 1][col] = s1;
          a0 = a1 = 0.f;
          ++c;
          b_next = __shfl(rpv, c + 1);
        }
        float wj = entw ? w[uu] : 1.f;
        a0 = fmaf(wj, fmaxf(bf2f(u[uu] & 0xffffu), 0.f), a0);
        a1 = fmaf(wj, fmaxf(bf2f(u[uu] >> 16),     0.f), a1);
      }
    }
    #pragma unroll 1
    for (;;) {                        // flush current + trailing (possibly empty) columns
      float s0 = a0, s1 = a1;
      if (segscale) { float sc = __shfl(invv, c); s0 *= sc; s1 *= sc; }
      int col = wv * 8 + c;
      sA[2 * lane][col]     = s0;
      sA[2 * lane + 1][col] = s1;
      a0 = a1 = 0.f;
      if (++c >= 8) break;
    }
  }
  __syncthreads();

  float acc[2][8];
  #pragma unroll
  for (int i = 0; i < 2; ++i)
    #pragma unroll
    for (int j = 0; j < 8; ++j) acc[i][j] = 0.f;

  #pragma unroll 1
  for (int k0 = 0; k0 < 128; k0 += 32) {
    #pragma unroll
    for (int j = 0; j < 4; ++j) {
      int idx = t * 4 + j * 1024;
      int kk = idx >> 7, c = idx & 127;
      *(float4*)&sW[kk][c] = *(const float4*)(W + (size_t)(k0 + kk) * 128 + c);
    }
    __syncthreads();
    #pragma unroll
    for (int kk = 0; kk < 32; ++kk) {
      float a2[2], w8[8];
      *(float2*)&a2[0] = *(const float2*)&sA[k0 + kk][tr * 2];
      *(float4*)&w8[0] = *(const float4*)&sW[kk][tc * 4];
      *(float4*)&w8[4] = *(const float4*)&sW[kk][64 + tc * 4];
      #pragma unroll
      for (int i = 0; i < 2; ++i)
        #pragma unroll
        for (int j = 0; j < 8; ++j)
          acc[i][j] = fmaf(a2[i], w8[j], acc[i][j]);
    }
    __syncthreads();
  }

  #pragma unroll
  for (int i = 0; i < 2; ++i) {
    int seg = seg0 + tr * 2 + i;
    if (seg >= nseg) continue;
    float o[8];
    #pragma unroll
    for (int j = 0; j < 8; ++j) o[j] = acc[i][j];
    float* p = OUT + (size_t)seg * 128;
    if (beta) {
      float4 c0 = *(const float4*)(p + tc * 4), c1 = *(const float4*)(p + 64 + tc * 4);
      o[0] += c0.x; o[1] += c0.y; o[2] += c0.z; o[3] += c0.w;
      o[4] += c1.x; o[5] += c1.y; o[6] += c1.z; o[7] += c1.w;
    }
    *(float4*)(p + tc * 4)      = *(const float4*)&o[0];
    *(float4*)(p + 64 + tc * 4) = *(const float4*)&o[4];
  }
}

// ---------------- gather segment-mean (128-wide), O[seg] += mean ----------------
// 8 row-loads in flight, predicated accumulate (no serial remainder).
__global__ __launch_bounds__(256)
void k_gsum(const int* __restrict__ rp, const int* __restrict__ ent,
            const float* __restrict__ SRC, float* __restrict__ O, int nseg)
{
  int wv = threadIdx.x >> 6, lane = threadIdx.x & 63;
  int seg = blockIdx.x * 4 + wv;
  if (seg >= nseg) return;
  int p0 = rp[seg], p1 = rp[seg + 1];
  if (p0 >= p1) return;
  float a0 = 0.f, a1 = 0.f;
  #pragma unroll 1
  for (int j = p0; j < p1; j += 8) {
    int ids[8];
    #pragma unroll
    for (int i = 0; i < 8; ++i) {
      int jj = j + i; jj = jj < p1 ? jj : p1 - 1;
      ids[i] = ent[jj];
    }
    float2 v[8];
    #pragma unroll
    for (int i = 0; i < 8; ++i)
      v[i] = ((const float2*)(SRC + (size_t)ids[i] * 128))[lane];
    #pragma unroll
    for (int i = 0; i < 8; ++i) {
      bool ok = (j + i) < p1;
      a0 += ok ? v[i].x : 0.f;
      a1 += ok ? v[i].y : 0.f;
    }
  }
  float sc = 1.f / fmaxf((float)(p1 - p0), 1.f);
  float2* orow = (float2*)(O + (size_t)seg * 128);
  float2 cur = orow[lane];
  cur.x += a0 * sc; cur.y += a1 * sc;
  orow[lane] = cur;
}

// ---------------- fused attention: online softmax + PV, one wave per node ----------------
// 4 entries/batch: 8 loads in flight, 4 parallel shuffle-reduce chains,
// one online-softmax rescale per batch.
__global__ __launch_bounds__(256)
void k_attn(const int* __restrict__ rp, const int* __restrict__ ent,
            const float* __restrict__ q, const float* __restrict__ kb,
            const float* __restrict__ vb, float* __restrict__ o, int nseg)
{
  int wv = threadIdx.x >> 6, lane = threadIdx.x & 63;
  int seg = blockIdx.x * 4 + wv;
  if (seg >= nseg) return;
  int p0 = rp[seg], p1 = rp[seg + 1];
  if (p0 >= p1) return;
  float2 q2 = ((const float2*)(q + (size_t)seg * 128))[lane];
  float m = -1e30f, l = 0.f, o0 = 0.f, o1 = 0.f;
  #pragma unroll 1
  for (int j = p0; j < p1; j += 4) {
    int s[4];
    #pragma unroll
    for (int i = 0; i < 4; ++i) {
      int jj = j + i; jj = jj < p1 ? jj : p1 - 1;
      s[i] = ent[jj];
    }
    float2 k2[4], v2[4];
    #pragma unroll
    for (int i = 0; i < 4; ++i)
      k2[i] = ((const float2*)(kb + (size_t)s[i] * 128))[lane];
    #pragma unroll
    for (int i = 0; i < 4; ++i)
      v2[i] = ((const float2*)(vb + (size_t)s[i] * 128))[lane];
    float d[4];
    #pragma unroll
    for (int i = 0; i < 4; ++i) d[i] = fmaf(q2.x, k2[i].x, q2.y * k2[i].y);
    #pragma unroll
    for (int off = 1; off < 64; off <<= 1) {
      #pragma unroll
      for (int i = 0; i < 4; ++i) d[i] += __shfl_xor(d[i], off);
    }
    float sc[4];
    #pragma unroll
    for (int i = 0; i < 4; ++i) {
      float v = d[i] * 0.088388347648318447f;      // 1/sqrt(128)
      v = v > 0.f ? v : 0.2f * v;                  // leaky 0.2
      sc[i] = (j + i < p1) ? v : -1e30f;
    }
    float mb = fmaxf(fmaxf(sc[0], sc[1]), fmaxf(sc[2], sc[3]));
    float mn = fmaxf(m, mb);
    float scale = expf(m - mn);
    float e[4];
    #pragma unroll
    for (int i = 0; i < 4; ++i)
      e[i] = (j + i < p1) ? expf(sc[i] - mn) : 0.f;
    l  = l  * scale + ((e[0] + e[1]) + (e[2] + e[3]));
    o0 = o0 * scale + ((e[0] * v2[0].x + e[1] * v2[1].x) + (e[2] * v2[2].x + e[3] * v2[3].x));
    o1 = o1 * scale + ((e[0] * v2[0].y + e[1] * v2[1].y) + (e[2] * v2[2].y + e[3] * v2[3].y));
    m = mn;
  }
  float inv = 1.f / fmaxf(l, 1e-9f);
  float2* orow = (float2*)(o + (size_t)seg * 128);
  float2 cur = orow[lane];
  cur.x += o0 * inv; cur.y += o1 * inv;
  orow[lane] = cur;
}

// ---------------- classifier + log_softmax ----------------
__global__ __launch_bounds__(256)
void k_out(const float* __restrict__ attn, const float* __restrict__ Wout,
           float* __restrict__ out, int n) {
  __shared__ float sW[128 * 64];
  for (int i = threadIdx.x; i < 128 * 64; i += 256) sW[i] = Wout[i];
  __syncthreads();
  int wave = threadIdx.x >> 6, lane = threadIdx.x & 63;
  int row = blockIdx.x * 4 + wave;
  if (row >= n) return;
  const float* a = attn + (size_t)row * 128;
  float z = 0.f;
  #pragma unroll 8
  for (int k = 0; k < 128; ++k) z = fmaf(a[k], sW[k * 64 + lane], z);
  float mx = z;
  #pragma unroll
  for (int off = 32; off; off >>= 1) mx = fmaxf(mx, __shfl_xor(mx, off));
  float ee = expf(z - mx);
  float ss = ee;
  #pragma unroll
  for (int off = 32; off; off >>= 1) ss += __shfl_xor(ss, off);
  out[(size_t)row * 64 + lane] = z - mx - logf(ss);
}

extern "C" void kernel_launch(void* const* d_in, const int* in_sizes, int n_in,
                              void* d_out, int out_size, void* d_ws, size_t ws_size,
                              hipStream_t stream) {
  (void)in_sizes; (void)n_in; (void)out_size;
  const float* x        = (const float*)d_in[0];
  const float* et       = (const float*)d_in[1];
  const int*   H0       = (const int*)d_in[2];
  const int*   H1       = H0 + Ee;
  const int*   src      = (const int*)d_in[3];
  const int*   dst      = src + Ee;
  const int*   src_lg   = (const int*)d_in[4];
  const int*   dst_lg   = src_lg + LGEe;
  const float* W_tsa1_s = (const float*)d_in[5];
  const float* W_tsa1_n = (const float*)d_in[6];
  const float* W_tsa2_s = (const float*)d_in[7];
  const float* W_tsa2_n = (const float*)d_in[8];
  const float* W_etn    = (const float*)d_in[9];
  const float* W_eg_lin = (const float*)d_in[10];
  const float* W_ea_s   = (const float*)d_in[11];
  const float* W_ea_n   = (const float*)d_in[12];
  const float* W_an1_s  = (const float*)d_in[13];
  const float* W_an1_n  = (const float*)d_in[14];
  const float* W_an2_s  = (const float*)d_in[15];
  const float* W_an2_n  = (const float*)d_in[16];
  const float* Wq       = (const float*)d_in[17];
  const float* Wk       = (const float*)d_in[18];
  const float* Wv       = (const float*)d_in[19];
  const float* W_out    = (const float*)d_in[20];
  float* out = (float*)d_out;

  // ---- workspace carve ----
  char* wp = (char*)d_ws;
  size_t avail = ws_size;
  auto alloc = [&](size_t bytes) -> void* {
    void* r = (void*)wp;
    size_t pad = (bytes + 255) & ~(size_t)255;
    wp += pad; avail = (avail >= pad) ? avail - pad : 0;
    return r;
  };
  const size_t NH = (size_t)Nn * 128;
  unsigned short* BUF = (unsigned short*)alloc((size_t)Ee * 128 * 2); // 204.8MB bf16 h1
  float* agg   = (float*)alloc(NH * 4);
  int* ptrA  = (int*)alloc(((size_t)Ee + 1) * 4);
  int* cntA  = (int*)alloc((size_t)Ee * 4);
  int* entA  = (int*)alloc((size_t)LGEe * 4);
  int* ptrB  = (int*)alloc(((size_t)Nn + 1) * 4);
  int* cntB  = (int*)alloc((size_t)Nn * 4);
  int* entBs = (int*)alloc((size_t)2 * LGEe * 4);
  float* entBw = (float*)alloc((size_t)2 * LGEe * 4);
  int* ptrC  = (int*)alloc(((size_t)Nn + 1) * 4);
  int* cntC  = (int*)alloc((size_t)Nn * 4);
  int* entC  = (int*)alloc((size_t)2 * Ee * 4);
  int* ptrD  = (int*)alloc(((size_t)Nn + 1) * 4);
  int* cntD  = (int*)alloc((size_t)Nn * 4);
  int* entD  = (int*)alloc((size_t)Ee * 4);
  float* rdegN = (float*)alloc((size_t)Nn * 4);
  int* bsum  = (int*)alloc(2048 * 4);
  if (avail == 0 && wp > (char*)d_ws + ws_size) return;  // ws too small: clean fail

  // node-phase f32 arrays overlay BUF (dead after agg is built): 8 x 25.6MB
  float* er  = (float*)BUF + 0 * NH;
  float* ae  = (float*)BUF + 1 * NH;
  float* hn  = (float*)BUF + 2 * NH;
  float* hn2 = (float*)BUF + 3 * NH;
  float* qb  = (float*)BUF + 4 * NH;
  float* kb  = (float*)BUF + 5 * NH;
  float* vb  = (float*)BUF + 6 * NH;
  float* tmp = (float*)BUF + 7 * NH;

  auto cdiv = [](long a, long b) { return (int)((a + b - 1) / b); };
  auto scan = [&](int* cnt, int* ptr, int n, int total) {
    int nb = cdiv(n, 1024);
    k_scan1<<<nb, 256, 0, stream>>>(cnt, ptr, bsum, n);
    k_scan2<<<1, 1024, 0, stream>>>(bsum, nb);
    k_scan3<<<cdiv(n, 256), 256, 0, stream>>>(ptr, bsum, n, total);
  };

  const int gLG = cdiv(LGEe, 256), gEe = cdiv(Ee, 256);

  // ---- CSR A: line-graph by dst_lg (E segments) ----
  hipMemsetAsync(cntA, 0, (size_t)Ee * 4, stream);
  k_count_direct<<<gLG, 256, 0, stream>>>(dst_lg, cntA, LGEe);
  scan(cntA, ptrA, Ee, LGEe);
  hipMemsetAsync(cntA, 0, (size_t)Ee * 4, stream);
  k_fillA<<<gLG, 256, 0, stream>>>(dst_lg, src_lg, ptrA, cntA, entA, LGEe);

  // ---- CSR B: composed H[b][dst_lg[m]] (N segments, 2*LGE entries) ----
  hipMemsetAsync(cntB, 0, (size_t)Nn * 4, stream);
  k_count_comp<<<gLG, 256, 0, stream>>>(H0, dst_lg, cntB, LGEe);
  k_count_comp<<<gLG, 256, 0, stream>>>(H1, dst_lg, cntB, LGEe);
  scan(cntB, ptrB, Nn, 2 * LGEe);
  hipMemsetAsync(cntB, 0, (size_t)Nn * 4, stream);
  k_fillB<<<gLG, 256, 0, stream>>>(H0, dst_lg, src_lg, ptrA, ptrB, cntB, entBs, entBw, LGEe);
  k_fillB<<<gLG, 256, 0, stream>>>(H1, dst_lg, src_lg, ptrA, ptrB, cntB, entBs, entBw, LGEe);

  // ---- CSR C: H incidence (N segments, 2*E entries, value = edge id) ----
  hipMemsetAsync(cntC, 0, (size_t)Nn * 4, stream);
  k_count_direct<<<gEe, 256, 0, stream>>>(H0, cntC, Ee);
  k_count_direct<<<gEe, 256, 0, stream>>>(H1, cntC, Ee);
  scan(cntC, ptrC, Nn, 2 * Ee);
  hipMemsetAsync(cntC, 0, (size_t)Nn * 4, stream);
  k_fillC<<<gEe, 256, 0, stream>>>(H0, ptrC, cntC, entC, Ee);
  k_fillC<<<gEe, 256, 0, stream>>>(H1, ptrC, cntC, entC, Ee);

  // ---- CSR D: raw graph by dst (N segments, E entries, value = src) ----
  hipMemsetAsync(cntD, 0, (size_t)Nn * 4, stream);
  k_count_direct<<<gEe, 256, 0, stream>>>(dst, cntD, Ee);
  scan(cntD, ptrD, Nn, Ee);
  hipMemsetAsync(cntD, 0, (size_t)Nn * 4, stream);
  k_fillD<<<gEe, 256, 0, stream>>>(dst, src, ptrD, cntD, entD, Ee);
  k_rdeg<<<cdiv(Nn, 256), 256, 0, stream>>>(ptrC, rdegN, Nn);

  const int gN128 = cdiv(Nn, 128);      // 391
  const int gN32  = cdiv(Nn, 32);       // 1563
  const int gW    = cdiv(Nn, 4);        // 12500

  // ---- TSA layer 1, fused self+nbr -> BUF (bf16, pre-relu), split-bf16 MFMA ----
  k_tsa1<<<Ee / 64, 256, 0, stream>>>(et, ptrA, entA, W_tsa1_s, W_tsa1_n, BUF);

  // ---- TSA layer 2 + EdgeToNode fused at N-scale (agg = P@W2s + Q@W2n) ----
  k_gg2<<<gN32, 256, 0, stream>>>(Nn, ptrC, entC, nullptr, 0, BUF, W_tsa2_s, agg, 0);
  k_gg2<<<gN32, 256, 0, stream>>>(Nn, ptrB, entBs, entBw, 0, BUF, W_tsa2_n, agg, 1);
  k_gemm128<<<gN128, 256, 0, stream>>>(Nn, agg, 128, W_etn, rdegN, 0, 2, tmp);
  k_gemm128<<<gN128, 256, 0, stream>>>(Nn, tmp, 128, W_eg_lin, nullptr, 0, 0, er);

  // ---- edge_aggr SAGE ----
  k_gemm128<<<gN128, 256, 0, stream>>>(Nn, er, 128, W_ea_s, nullptr, 0, 0, ae);
  k_gemm128<<<gN128, 256, 0, stream>>>(Nn, er, 128, W_ea_n, nullptr, 0, 0, tmp);
  k_gsum<<<gW, 256, 0, stream>>>(ptrD, entD, tmp, ae, Nn);

  // ---- attr_node_model (hn kept pre-relu; relu applied on read) ----
  k_gemm128<<<gN128, 256, 0, stream>>>(Nn, x, 256, W_an1_s, nullptr, 0, 0, hn);
  k_gemm128<<<gN128, 256, 0, stream>>>(Nn, x, 256, W_an1_n, nullptr, 0, 0, tmp);
  k_gsum<<<gW, 256, 0, stream>>>(ptrD, entD, tmp, hn, Nn);
  k_gemm128<<<gN128, 256, 0, stream>>>(Nn, hn, 128, W_an2_s, nullptr, 1, 0, hn2);
  k_gemm128<<<gN128, 256, 0, stream>>>(Nn, hn, 128, W_an2_n, nullptr, 1, 0, tmp);
  k_gsum<<<gW, 256, 0, stream>>>(ptrD, entD, tmp, hn2, Nn);

  // ---- MixAttention (fused online softmax; out accumulated into hn2) ----
  k_gemm128<<<gN128, 256, 0, stream>>>(Nn, hn2, 128, Wq, nullptr, 0, 0, qb);
  k_gemm128<<<gN128, 256, 0, stream>>>(Nn, ae, 128, Wk, nullptr, 0, 0, kb);
  k_gemm128<<<gN128, 256, 0, stream>>>(Nn, ae, 128, Wv, nullptr, 0, 0, vb);
  k_attn<<<gW, 256, 0, stream>>>(ptrD, entD, qb, kb, vb, hn2, Nn);

  // ---- classifier + log_softmax ----
  k_out<<<gW, 256, 0, stream>>>(hn2, W_out, out, Nn);
}

// Round 5
// 2811.869 us; speedup vs baseline: 1.3179x; 1.0154x over previous
//
#include <hip/hip_runtime.h>
#include <cstddef>

static constexpr int Nn   = 50000;
static constexpr int Ee   = 800000;
static constexpr int LGEe = 1600000;

typedef __attribute__((ext_vector_type(8))) short bf16x8;
typedef __attribute__((ext_vector_type(4))) float f32x4;

__device__ __forceinline__ float bf2f(unsigned int u16) {
  return __uint_as_float(u16 << 16);
}
__device__ __forceinline__ unsigned int f2bf(float f) {
  unsigned int u = __float_as_uint(f);
  u += 0x7fffu + ((u >> 16) & 1u);   // RNE
  return u >> 16;
}

// ---------------- CSR build kernels ----------------
__global__ __launch_bounds__(256)
void k_count_direct(const int* __restrict__ idx, int* __restrict__ cnt, int n) {
  int i = blockIdx.x * 256 + threadIdx.x;
  if (i < n) atomicAdd(&cnt[idx[i]], 1);
}
__global__ __launch_bounds__(256)
void k_count_comp(const int* __restrict__ Hrow, const int* __restrict__ dlg,
                  int* __restrict__ cnt, int n) {
  int i = blockIdx.x * 256 + threadIdx.x;
  if (i < n) atomicAdd(&cnt[Hrow[dlg[i]]], 1);
}
__global__ __launch_bounds__(256)
void k_scan1(const int* __restrict__ in, int* __restrict__ out,
             int* __restrict__ bsum, int n) {
  __shared__ int sd[256];
  int tid = threadIdx.x;
  int base = blockIdx.x * 1024 + tid * 4;
  int4 v = {0, 0, 0, 0};
  if (base < n) v = *(const int4*)(in + base);   // n % 4 == 0 for all uses
  int s = v.x + v.y + v.z + v.w;
  sd[tid] = s; __syncthreads();
  for (int off = 1; off < 256; off <<= 1) {
    int t_ = (tid >= off) ? sd[tid - off] : 0; __syncthreads();
    sd[tid] += t_; __syncthreads();
  }
  int excl = sd[tid] - s;
  if (base < n) {
    int4 o; o.x = excl; o.y = o.x + v.x; o.z = o.y + v.y; o.w = o.z + v.z;
    *(int4*)(out + base) = o;
  }
  if (tid == 255) bsum[blockIdx.x] = sd[255];
}
__global__ __launch_bounds__(1024)
void k_scan2(int* __restrict__ b, int nb) {
  __shared__ int sd[1024];
  int tid = threadIdx.x;
  int v = (tid < nb) ? b[tid] : 0;
  sd[tid] = v; __syncthreads();
  for (int off = 1; off < 1024; off <<= 1) {
    int t_ = (tid >= off) ? sd[tid - off] : 0; __syncthreads();
    sd[tid] += t_; __syncthreads();
  }
  if (tid < nb) b[tid] = sd[tid] - v;
}
__global__ __launch_bounds__(256)
void k_scan3(int* __restrict__ out, const int* __restrict__ bsum, int n, int total) {
  int i = blockIdx.x * 256 + threadIdx.x;
  if (i < n) out[i] += bsum[i >> 10];
  if (i == 0) out[n] = total;
}
__global__ __launch_bounds__(256)
void k_fillA(const int* __restrict__ dlg, const int* __restrict__ slg,
             const int* __restrict__ ptr, int* __restrict__ cur,
             int* __restrict__ ent, int n) {
  int m = blockIdx.x * 256 + threadIdx.x;
  if (m >= n) return;
  int d = dlg[m];
  int pos = ptr[d] + atomicAdd(&cur[d], 1);
  ent[pos] = slg[m];
}
__global__ __launch_bounds__(256)
void k_fillB(const int* __restrict__ Hrow, const int* __restrict__ dlg,
             const int* __restrict__ slg, const int* __restrict__ ptrA,
             const int* __restrict__ ptrB, int* __restrict__ cur,
             int* __restrict__ entS, float* __restrict__ entW, int n) {
  int m = blockIdx.x * 256 + threadIdx.x;
  if (m >= n) return;
  int d = dlg[m];
  int seg = Hrow[d];
  int pos = ptrB[seg] + atomicAdd(&cur[seg], 1);
  entS[pos] = slg[m];
  int la = ptrA[d + 1] - ptrA[d];
  entW[pos] = 1.0f / (float)max(la, 1);
}
__global__ __launch_bounds__(256)
void k_fillC(const int* __restrict__ Hrow, const int* __restrict__ ptr,
             int* __restrict__ cur, int* __restrict__ ent, int n) {
  int e = blockIdx.x * 256 + threadIdx.x;
  if (e >= n) return;
  int seg = Hrow[e];
  int pos = ptr[seg] + atomicAdd(&cur[seg], 1);
  ent[pos] = e;
}
__global__ __launch_bounds__(256)
void k_fillD(const int* __restrict__ dstA, const int* __restrict__ srcA,
             const int* __restrict__ ptr, int* __restrict__ cur,
             int* __restrict__ ent, int n) {
  int e = blockIdx.x * 256 + threadIdx.x;
  if (e >= n) return;
  int seg = dstA[e];
  int pos = ptr[seg] + atomicAdd(&cur[seg], 1);
  ent[pos] = srcA[e];
}
__global__ __launch_bounds__(256)
void k_rdeg(const int* __restrict__ ptr, float* __restrict__ r, int n) {
  int i = blockIdx.x * 256 + threadIdx.x;
  if (i < n) r[i] = 1.0f / fmaxf((float)(ptr[i + 1] - ptr[i]), 1.0f);
}

// ---------------- dense GEMM: C[Mx128] = act( rowmul(reluA(A)) @ W ) + beta*C ----
__global__ __launch_bounds__(256)
void k_gemm128(int M, const float* __restrict__ A, int K,
               const float* __restrict__ W, const float* __restrict__ dgA,
               int reluA, int act, float* __restrict__ C, int beta)
{
  __shared__ float sA[32][132];
  __shared__ float sW[32][132];
  const int t = threadIdx.x, tr = t >> 4, tc = t & 15;
  const int row0 = blockIdx.x * 128;
  float acc[8][8];
  #pragma unroll
  for (int i = 0; i < 8; ++i)
    #pragma unroll
    for (int j = 0; j < 8; ++j) acc[i][j] = 0.f;

  #pragma unroll 1
  for (int k0 = 0; k0 < K; k0 += 32) {
    __syncthreads();
    #pragma unroll
    for (int j = 0; j < 4; ++j) {
      int idx = t * 4 + j * 1024;
      int r = idx >> 5, kk = idx & 31;
      int gr = row0 + r; if (gr > M - 1) gr = M - 1;
      float4 va = *(const float4*)(A + (size_t)gr * K + k0 + kk);
      if (reluA) {
        va.x = fmaxf(va.x, 0.f); va.y = fmaxf(va.y, 0.f);
        va.z = fmaxf(va.z, 0.f); va.w = fmaxf(va.w, 0.f);
      }
      if (dgA) {
        float sc = dgA[gr];
        va.x *= sc; va.y *= sc; va.z *= sc; va.w *= sc;
      }
      sA[kk + 0][r] = va.x; sA[kk + 1][r] = va.y;
      sA[kk + 2][r] = va.z; sA[kk + 3][r] = va.w;
    }
    #pragma unroll
    for (int j = 0; j < 4; ++j) {
      int idx = t * 4 + j * 1024;
      int kk = idx >> 7, c = idx & 127;
      *(float4*)&sW[kk][c] = *(const float4*)(W + (size_t)(k0 + kk) * 128 + c);
    }
    __syncthreads();
    #pragma unroll
    for (int kk = 0; kk < 32; ++kk) {
      float a[8], w[8];
      *(float4*)&a[0] = *(const float4*)&sA[kk][tr * 4];
      *(float4*)&a[4] = *(const float4*)&sA[kk][64 + tr * 4];
      *(float4*)&w[0] = *(const float4*)&sW[kk][tc * 4];
      *(float4*)&w[4] = *(const float4*)&sW[kk][64 + tc * 4];
      #pragma unroll
      for (int i = 0; i < 8; ++i)
        #pragma unroll
        for (int j = 0; j < 8; ++j)
          acc[i][j] = fmaf(a[i], w[j], acc[i][j]);
    }
  }
  #pragma unroll 1
  for (int i = 0; i < 8; ++i) {
    int gr = row0 + (i & 4) * 16 + tr * 4 + (i & 3);
    if (gr >= M) continue;
    float o[8];
    #pragma unroll
    for (int j = 0; j < 8; ++j) {
      float vv = acc[i][j];
      if (act == 1)      vv = fmaxf(vv, 0.f);
      else if (act == 2) vv = vv > 0.f ? vv : vv * 0.2f;
      o[j] = vv;
    }
    float* p = C + (size_t)gr * 128;
    if (beta) {
      float4 c0 = *(const float4*)(p + tc * 4), c1 = *(const float4*)(p + 64 + tc * 4);
      o[0] += c0.x; o[1] += c0.y; o[2] += c0.z; o[3] += c0.w;
      o[4] += c1.x; o[5] += c1.y; o[6] += c1.z; o[7] += c1.w;
    }
    *(float4*)(p + tc * 4)      = *(const float4*)&o[0];
    *(float4*)(p + 64 + tc * 4) = *(const float4*)&o[4];
  }
}

// ---------------- fused TSA1 (split-bf16 MFMA): ----------------
// BUF[e] = bf16( et[e]@Ws + mean_{s in A(e)} et[s] @ Wn ), 64 segs/block.
__global__ __launch_bounds__(256)
void k_tsa1(const float* __restrict__ et,
            const int* __restrict__ rp, const int* __restrict__ ent,
            const float* __restrict__ Ws, const float* __restrict__ Wn,
            unsigned short* __restrict__ BUF)
{
  __shared__ __align__(16) unsigned char smem[34816];
  unsigned short* sAh = (unsigned short*)smem;            // [64][128] bf16 hi
  unsigned short* sAl = (unsigned short*)(smem + 16384);  // [64][128] bf16 lo
  int*   sEnt  = (int*)(smem + 32768);                    // 512 ints
  float* stage = (float*)smem;                            // [64][132] f32 (epilogue)

  const int t = threadIdx.x, wv = t >> 6, lane = t & 63;
  const int tr = t >> 4, tc = t & 15;
  const int nrow = lane & 15, kg = lane >> 4;
  const int seg0 = blockIdx.x * 64;
  const int segbase = seg0 + wv * 16;

  // lanes 0..16 hold row pointers of this wave's 16 segments
  int rpv = (lane <= 16) ? rp[segbase + lane] : 0;
  int nxtv = __shfl(rpv, (lane + 1) & 63);
  float invv = 1.f / fmaxf((float)(nxtv - rpv), 1.f);   // valid lanes 0..15

  // cache block's contiguous ent slice (coalesced); >512 falls back to global
  const int base = rp[seg0];
  const int cnt  = rp[seg0 + 64] - base;
  const int lim  = cnt < 512 ? cnt : 512;
  for (int i = t; i < lim; i += 256) sEnt[i] = ent[base + i];

  // direct half (k = lane): coalesced loads, split hi/lo, swizzled b16 writes
  {
    float dv[16];
    #pragma unroll
    for (int i = 0; i < 16; ++i)
      dv[i] = et[(size_t)(segbase + i) * 64 + lane];
    #pragma unroll
    for (int i = 0; i < 16; ++i) {
      int ss = wv * 16 + i;
      unsigned int hi = f2bf(dv[i]);
      float lo = dv[i] - bf2f(hi);
      int idx = ss * 128 + (lane ^ ((ss & 7) << 3));
      sAh[idx] = (unsigned short)hi;
      sAl[idx] = (unsigned short)f2bf(lo);
    }
  }

  // B fragments from global (W is L2-resident): lane supplies
  // B[k = kg*8+j][n = ntile*16 + nrow] for its wave's 2 n-tiles x 4 k-chunks.
  bf16x8 Bh[2][4], Bl[2][4];
  #pragma unroll
  for (int np = 0; np < 2; ++np) {
    int n = (wv * 2 + np) * 16 + nrow;
    #pragma unroll
    for (int kc = 0; kc < 4; ++kc) {
      const float* Wp = (kc < 2) ? Ws : Wn;
      int kr0 = (kc & 1) * 32 + kg * 8;
      #pragma unroll
      for (int j = 0; j < 8; ++j) {
        float w = Wp[(size_t)(kr0 + j) * 128 + n];
        unsigned int hi = f2bf(w);
        float lo = w - bf2f(hi);
        Bh[np][kc][j] = (short)(unsigned short)hi;
        Bl[np][kc][j] = (short)(unsigned short)f2bf(lo);
      }
    }
  }
  __syncthreads();   // sEnt ready

  // gathered half (k = 64+lane): flatten over entries, 8 row-loads in flight
  {
    int q0 = __shfl(rpv, 0);
    int q1 = __shfl(rpv, 16);
    int c = 0;
    int b_next = __shfl(rpv, 1);
    float idg = __shfl(invv, 0);
    float a = 0.f;
    #pragma unroll 1
    for (int j = q0; j < q1; j += 8) {
      float x[8];
      #pragma unroll
      for (int u = 0; u < 8; ++u) {
        int jj = j + u; jj = jj < q1 ? jj : q1 - 1;
        int ix = jj - base;
        int s = (ix < 512) ? sEnt[ix] : ent[jj];
        x[u] = et[(size_t)s * 64 + lane];
      }
      #pragma unroll
      for (int u = 0; u < 8; ++u) {
        int jj = j + u;
        if (jj >= q1) break;
        while (jj >= b_next) {        // column c complete -> flush
          float v = a * idg;
          int ss = wv * 16 + c;
          unsigned int hi = f2bf(v);
          float lo = v - bf2f(hi);
          int idx = ss * 128 + ((64 + lane) ^ ((ss & 7) << 3));
          sAh[idx] = (unsigned short)hi;
          sAl[idx] = (unsigned short)f2bf(lo);
          a = 0.f;
          ++c;
          b_next = __shfl(rpv, c + 1);
          idg = __shfl(invv, c);
        }
        a += x[u];
      }
    }
    #pragma unroll 1
    for (;;) {                        // flush current + trailing columns
      float v = a * idg;
      int ss = wv * 16 + c;
      unsigned int hi = f2bf(v);
      float lo = v - bf2f(hi);
      int idx = ss * 128 + ((64 + lane) ^ ((ss & 7) << 3));
      sAh[idx] = (unsigned short)hi;
      sAl[idx] = (unsigned short)f2bf(lo);
      a = 0.f;
      if (++c >= 16) break;
      idg = __shfl(invv, c);
    }
  }
  __syncthreads();

  // MFMA: out[64 seg][128 feat], split product Ah*Bh + Al*Bh + Ah*Bl
  f32x4 acc[4][2];
  #pragma unroll
  for (int m = 0; m < 4; ++m)
    #pragma unroll
    for (int np = 0; np < 2; ++np)
      acc[m][np] = (f32x4){0.f, 0.f, 0.f, 0.f};

  #pragma unroll
  for (int kc = 0; kc < 4; ++kc) {
    #pragma unroll
    for (int m = 0; m < 4; ++m) {
      int ss = m * 16 + nrow;
      int kbase = kc * 32 + kg * 8;
      int idx = ss * 128 + (kbase ^ ((ss & 7) << 3));
      bf16x8 ah = *(const bf16x8*)(sAh + idx);
      bf16x8 al = *(const bf16x8*)(sAl + idx);
      #pragma unroll
      for (int np = 0; np < 2; ++np) {
        acc[m][np] = __builtin_amdgcn_mfma_f32_16x16x32_bf16(ah, Bh[np][kc], acc[m][np], 0, 0, 0);
        acc[m][np] = __builtin_amdgcn_mfma_f32_16x16x32_bf16(al, Bh[np][kc], acc[m][np], 0, 0, 0);
        acc[m][np] = __builtin_amdgcn_mfma_f32_16x16x32_bf16(ah, Bl[np][kc], acc[m][np], 0, 0, 0);
      }
    }
  }

  // epilogue: C/D frag (col=lane&15, row=(lane>>4)*4+r) -> f32 stage -> uint4
  __syncthreads();
  #pragma unroll
  for (int m = 0; m < 4; ++m)
    #pragma unroll
    for (int np = 0; np < 2; ++np)
      #pragma unroll
      for (int r = 0; r < 4; ++r)
        stage[(m * 16 + kg * 4 + r) * 132 + (wv * 2 + np) * 16 + nrow] = acc[m][np][r];
  __syncthreads();
  #pragma unroll
  for (int i = 0; i < 4; ++i) {
    int s = tr * 4 + i;
    const float* sp = stage + s * 132 + tc * 8;
    float4 v0 = *(const float4*)sp;
    float4 v1 = *(const float4*)(sp + 4);
    unsigned int pk[4];
    pk[0] = f2bf(v0.x) | (f2bf(v0.y) << 16);
    pk[1] = f2bf(v0.z) | (f2bf(v0.w) << 16);
    pk[2] = f2bf(v1.x) | (f2bf(v1.y) << 16);
    pk[3] = f2bf(v1.z) | (f2bf(v1.w) << 16);
    uint4 st = {pk[0], pk[1], pk[2], pk[3]};
    *(uint4*)(BUF + (size_t)(seg0 + s) * 128 + tc * 8) = st;
  }
}

// ---------------- balanced chunked pooling (bf16 rows, relu, opt weights) ----
// One wave per 256-entry chunk; binary-search rp for the start segment; flush
// chunk-owned segments with direct RMW, boundary segments with atomicAdd.
// O must be zero-initialized. O[seg] += sum_{j in seg} w_j * relu(SRC[ent[j]]).
__global__ __launch_bounds__(256)
void k_poolb(const int* __restrict__ rp, const int* __restrict__ ent,
             const float* __restrict__ entw,
             const unsigned short* __restrict__ SRC,
             float* __restrict__ O, int nseg, int total)
{
  const int wv = threadIdx.x >> 6, lane = threadIdx.x & 63;
  const int chunk = blockIdx.x * 4 + wv;
  const int c0 = chunk * 256;
  if (c0 >= total) return;
  int c1 = c0 + 256; if (c1 > total) c1 = total;

  int lo = 0, hi = nseg;                 // rp[lo] <= c0 < rp[hi]
  while (lo + 1 < hi) {
    int mid = (lo + hi) >> 1;
    if (rp[mid] <= c0) lo = mid; else hi = mid;
  }
  int seg = lo;
  int sstart = rp[seg];
  int send = rp[seg + 1];
  float a0 = 0.f, a1 = 0.f;

  #pragma unroll 1
  for (int j = c0; j < c1; j += 8) {
    int ids[8]; float w[8];
    #pragma unroll
    for (int u = 0; u < 8; ++u) {
      int jj = j + u; jj = jj < c1 ? jj : c1 - 1;
      ids[u] = ent[jj];
      w[u] = entw ? entw[jj] : 1.f;
    }
    unsigned int uv[8];
    #pragma unroll
    for (int u = 0; u < 8; ++u)
      uv[u] = *(const unsigned int*)(SRC + (size_t)ids[u] * 128 + 2 * lane);
    #pragma unroll
    for (int u = 0; u < 8; ++u) {
      int jj = j + u;
      if (jj >= c1) break;
      while (jj >= send) {               // segment complete -> flush
        float* p = O + (size_t)seg * 128;
        if (sstart >= c0 && send <= c1) {
          p[2 * lane]     += a0;
          p[2 * lane + 1] += a1;
        } else {
          atomicAdd(p + 2 * lane, a0);
          atomicAdd(p + 2 * lane + 1, a1);
        }
        a0 = a1 = 0.f;
        ++seg; sstart = send; send = rp[seg + 1];
      }
      a0 = fmaf(w[u], fmaxf(bf2f(uv[u] & 0xffffu), 0.f), a0);
      a1 = fmaf(w[u], fmaxf(bf2f(uv[u] >> 16),     0.f), a1);
    }
  }
  {                                       // final flush (possibly partial seg)
    float* p = O + (size_t)seg * 128;
    if (sstart >= c0 && send <= c1) {
      p[2 * lane]     += a0;
      p[2 * lane + 1] += a1;
    } else {
      atomicAdd(p + 2 * lane, a0);
      atomicAdd(p + 2 * lane + 1, a1);
    }
  }
}

// ---------------- balanced chunked segment-mean (f32 rows): O[seg] += mean ----
__global__ __launch_bounds__(256)
void k_poolf(const int* __restrict__ rp, const int* __restrict__ ent,
             const float* __restrict__ SRC, float* __restrict__ O,
             int nseg, int total)
{
  const int wv = threadIdx.x >> 6, lane = threadIdx.x & 63;
  const int chunk = blockIdx.x * 4 + wv;
  const int c0 = chunk * 256;
  if (c0 >= total) return;
  int c1 = c0 + 256; if (c1 > total) c1 = total;

  int lo = 0, hi = nseg;
  while (lo + 1 < hi) {
    int mid = (lo + hi) >> 1;
    if (rp[mid] <= c0) lo = mid; else hi = mid;
  }
  int seg = lo;
  int sstart = rp[seg];
  int send = rp[seg + 1];
  float a0 = 0.f, a1 = 0.f;

  #pragma unroll 1
  for (int j = c0; j < c1; j += 8) {
    int ids[8];
    #pragma unroll
    for (int u = 0; u < 8; ++u) {
      int jj = j + u; jj = jj < c1 ? jj : c1 - 1;
      ids[u] = ent[jj];
    }
    float2 v[8];
    #pragma unroll
    for (int u = 0; u < 8; ++u)
      v[u] = ((const float2*)(SRC + (size_t)ids[u] * 128))[lane];
    #pragma unroll
    for (int u = 0; u < 8; ++u) {
      int jj = j + u;
      if (jj >= c1) break;
      while (jj >= send) {               // segment complete -> flush mean
        float sc = 1.f / fmaxf((float)(send - sstart), 1.f);
        float* p = O + (size_t)seg * 128;
        if (sstart >= c0 && send <= c1) {
          p[2 * lane]     += a0 * sc;
          p[2 * lane + 1] += a1 * sc;
        } else {
          atomicAdd(p + 2 * lane, a0 * sc);
          atomicAdd(p + 2 * lane + 1, a1 * sc);
        }
        a0 = a1 = 0.f;
        ++seg; sstart = send; send = rp[seg + 1];
      }
      a0 += v[u].x; a1 += v[u].y;
    }
  }
  {
    float sc = 1.f / fmaxf((float)(send - sstart), 1.f);
    float* p = O + (size_t)seg * 128;
    if (sstart >= c0 && send <= c1) {
      p[2 * lane]     += a0 * sc;
      p[2 * lane + 1] += a1 * sc;
    } else {
      atomicAdd(p + 2 * lane, a0 * sc);
      atomicAdd(p + 2 * lane + 1, a1 * sc);
    }
  }
}

// ---------------- fused attention: online softmax + PV, one wave per node ----------------
__global__ __launch_bounds__(256)
void k_attn(const int* __restrict__ rp, const int* __restrict__ ent,
            const float* __restrict__ q, const float* __restrict__ kb,
            const float* __restrict__ vb, float* __restrict__ o, int nseg)
{
  int wv = threadIdx.x >> 6, lane = threadIdx.x & 63;
  int seg = blockIdx.x * 4 + wv;
  if (seg >= nseg) return;
  int p0 = rp[seg], p1 = rp[seg + 1];
  if (p0 >= p1) return;
  float2 q2 = ((const float2*)(q + (size_t)seg * 128))[lane];
  float m = -1e30f, l = 0.f, o0 = 0.f, o1 = 0.f;
  #pragma unroll 1
  for (int j = p0; j < p1; j += 4) {
    int s[4];
    #pragma unroll
    for (int i = 0; i < 4; ++i) {
      int jj = j + i; jj = jj < p1 ? jj : p1 - 1;
      s[i] = ent[jj];
    }
    float2 k2[4], v2[4];
    #pragma unroll
    for (int i = 0; i < 4; ++i)
      k2[i] = ((const float2*)(kb + (size_t)s[i] * 128))[lane];
    #pragma unroll
    for (int i = 0; i < 4; ++i)
      v2[i] = ((const float2*)(vb + (size_t)s[i] * 128))[lane];
    float d[4];
    #pragma unroll
    for (int i = 0; i < 4; ++i) d[i] = fmaf(q2.x, k2[i].x, q2.y * k2[i].y);
    #pragma unroll
    for (int off = 1; off < 64; off <<= 1) {
      #pragma unroll
      for (int i = 0; i < 4; ++i) d[i] += __shfl_xor(d[i], off);
    }
    float sc[4];
    #pragma unroll
    for (int i = 0; i < 4; ++i) {
      float v = d[i] * 0.088388347648318447f;      // 1/sqrt(128)
      v = v > 0.f ? v : 0.2f * v;                  // leaky 0.2
      sc[i] = (j + i < p1) ? v : -1e30f;
    }
    float mb = fmaxf(fmaxf(sc[0], sc[1]), fmaxf(sc[2], sc[3]));
    float mn = fmaxf(m, mb);
    float scale = expf(m - mn);
    float e[4];
    #pragma unroll
    for (int i = 0; i < 4; ++i)
      e[i] = (j + i < p1) ? expf(sc[i] - mn) : 0.f;
    l  = l  * scale + ((e[0] + e[1]) + (e[2] + e[3]));
    o0 = o0 * scale + ((e[0] * v2[0].x + e[1] * v2[1].x) + (e[2] * v2[2].x + e[3] * v2[3].x));
    o1 = o1 * scale + ((e[0] * v2[0].y + e[1] * v2[1].y) + (e[2] * v2[2].y + e[3] * v2[3].y));
    m = mn;
  }
  float inv = 1.f / fmaxf(l, 1e-9f);
  float2* orow = (float2*)(o + (size_t)seg * 128);
  float2 cur = orow[lane];
  cur.x += o0 * inv; cur.y += o1 * inv;
  orow[lane] = cur;
}

// ---------------- classifier + log_softmax ----------------
__global__ __launch_bounds__(256)
void k_out(const float* __restrict__ attn, const float* __restrict__ Wout,
           float* __restrict__ out, int n) {
  __shared__ float sW[128 * 64];
  for (int i = threadIdx.x; i < 128 * 64; i += 256) sW[i] = Wout[i];
  __syncthreads();
  int wave = threadIdx.x >> 6, lane = threadIdx.x & 63;
  int row = blockIdx.x * 4 + wave;
  if (row >= n) return;
  const float* a = attn + (size_t)row * 128;
  float z = 0.f;
  #pragma unroll 8
  for (int k = 0; k < 128; ++k) z = fmaf(a[k], sW[k * 64 + lane], z);
  float mx = z;
  #pragma unroll
  for (int off = 32; off; off >>= 1) mx = fmaxf(mx, __shfl_xor(mx, off));
  float ee = expf(z - mx);
  float ss = ee;
  #pragma unroll
  for (int off = 32; off; off >>= 1) ss += __shfl_xor(ss, off);
  out[(size_t)row * 64 + lane] = z - mx - logf(ss);
}

extern "C" void kernel_launch(void* const* d_in, const int* in_sizes, int n_in,
                              void* d_out, int out_size, void* d_ws, size_t ws_size,
                              hipStream_t stream) {
  (void)in_sizes; (void)n_in; (void)out_size;
  const float* x        = (const float*)d_in[0];
  const float* et       = (const float*)d_in[1];
  const int*   H0       = (const int*)d_in[2];
  const int*   H1       = H0 + Ee;
  const int*   src      = (const int*)d_in[3];
  const int*   dst      = src + Ee;
  const int*   src_lg   = (const int*)d_in[4];
  const int*   dst_lg   = src_lg + LGEe;
  const float* W_tsa1_s = (const float*)d_in[5];
  const float* W_tsa1_n = (const float*)d_in[6];
  const float* W_tsa2_s = (const float*)d_in[7];
  const float* W_tsa2_n = (const float*)d_in[8];
  const float* W_etn    = (const float*)d_in[9];
  const float* W_eg_lin = (const float*)d_in[10];
  const float* W_ea_s   = (const float*)d_in[11];
  const float* W_ea_n   = (const float*)d_in[12];
  const float* W_an1_s  = (const float*)d_in[13];
  const float* W_an1_n  = (const float*)d_in[14];
  const float* W_an2_s  = (const float*)d_in[15];
  const float* W_an2_n  = (const float*)d_in[16];
  const float* Wq       = (const float*)d_in[17];
  const float* Wk       = (const float*)d_in[18];
  const float* Wv       = (const float*)d_in[19];
  const float* W_out    = (const float*)d_in[20];
  float* out = (float*)d_out;

  // ---- workspace carve ----
  char* wp = (char*)d_ws;
  size_t avail = ws_size;
  auto alloc = [&](size_t bytes) -> void* {
    void* r = (void*)wp;
    size_t pad = (bytes + 255) & ~(size_t)255;
    wp += pad; avail = (avail >= pad) ? avail - pad : 0;
    return r;
  };
  const size_t NH = (size_t)Nn * 128;
  unsigned short* BUF = (unsigned short*)alloc((size_t)Ee * 128 * 2); // 204.8MB bf16 h1
  float* agg   = (float*)alloc(NH * 4);
  int* ptrA  = (int*)alloc(((size_t)Ee + 1) * 4);
  int* cntA  = (int*)alloc((size_t)Ee * 4);
  int* entA  = (int*)alloc((size_t)LGEe * 4);
  int* ptrB  = (int*)alloc(((size_t)Nn + 1) * 4);
  int* cntB  = (int*)alloc((size_t)Nn * 4);
  int* entBs = (int*)alloc((size_t)2 * LGEe * 4);
  float* entBw = (float*)alloc((size_t)2 * LGEe * 4);
  int* ptrC  = (int*)alloc(((size_t)Nn + 1) * 4);
  int* cntC  = (int*)alloc((size_t)Nn * 4);
  int* entC  = (int*)alloc((size_t)2 * Ee * 4);
  int* ptrD  = (int*)alloc(((size_t)Nn + 1) * 4);
  int* cntD  = (int*)alloc((size_t)Nn * 4);
  int* entD  = (int*)alloc((size_t)Ee * 4);
  float* rdegN = (float*)alloc((size_t)Nn * 4);
  int* bsum  = (int*)alloc(2048 * 4);
  if (avail == 0 && wp > (char*)d_ws + ws_size) return;  // ws too small: clean fail

  // node-phase f32 arrays overlay BUF (dead after pools are built): 8 x 25.6MB
  float* er  = (float*)BUF + 0 * NH;
  float* ae  = (float*)BUF + 1 * NH;
  float* hn  = (float*)BUF + 2 * NH;
  float* hn2 = (float*)BUF + 3 * NH;
  float* qb  = (float*)BUF + 4 * NH;
  float* kb  = (float*)BUF + 5 * NH;
  float* vb  = (float*)BUF + 6 * NH;
  float* tmp = (float*)BUF + 7 * NH;
  // T (25.6MB) overlays entBs+entBw (contiguous, dead after pool2 consumes them)
  float* T = (float*)entBs;

  auto cdiv = [](long a, long b) { return (int)((a + b - 1) / b); };
  auto scan = [&](int* cnt, int* ptr, int n, int total) {
    int nb = cdiv(n, 1024);
    k_scan1<<<nb, 256, 0, stream>>>(cnt, ptr, bsum, n);
    k_scan2<<<1, 1024, 0, stream>>>(bsum, nb);
    k_scan3<<<cdiv(n, 256), 256, 0, stream>>>(ptr, bsum, n, total);
  };

  const int gLG = cdiv(LGEe, 256), gEe = cdiv(Ee, 256);

  // ---- CSR A: line-graph by dst_lg (E segments) ----
  hipMemsetAsync(cntA, 0, (size_t)Ee * 4, stream);
  k_count_direct<<<gLG, 256, 0, stream>>>(dst_lg, cntA, LGEe);
  scan(cntA, ptrA, Ee, LGEe);
  hipMemsetAsync(cntA, 0, (size_t)Ee * 4, stream);
  k_fillA<<<gLG, 256, 0, stream>>>(dst_lg, src_lg, ptrA, cntA, entA, LGEe);

  // ---- CSR B: composed H[b][dst_lg[m]] (N segments, 2*LGE entries) ----
  hipMemsetAsync(cntB, 0, (size_t)Nn * 4, stream);
  k_count_comp<<<gLG, 256, 0, stream>>>(H0, dst_lg, cntB, LGEe);
  k_count_comp<<<gLG, 256, 0, stream>>>(H1, dst_lg, cntB, LGEe);
  scan(cntB, ptrB, Nn, 2 * LGEe);
  hipMemsetAsync(cntB, 0, (size_t)Nn * 4, stream);
  k_fillB<<<gLG, 256, 0, stream>>>(H0, dst_lg, src_lg, ptrA, ptrB, cntB, entBs, entBw, LGEe);
  k_fillB<<<gLG, 256, 0, stream>>>(H1, dst_lg, src_lg, ptrA, ptrB, cntB, entBs, entBw, LGEe);

  // ---- CSR C: H incidence (N segments, 2*E entries, value = edge id) ----
  hipMemsetAsync(cntC, 0, (size_t)Nn * 4, stream);
  k_count_direct<<<gEe, 256, 0, stream>>>(H0, cntC, Ee);
  k_count_direct<<<gEe, 256, 0, stream>>>(H1, cntC, Ee);
  scan(cntC, ptrC, Nn, 2 * Ee);
  hipMemsetAsync(cntC, 0, (size_t)Nn * 4, stream);
  k_fillC<<<gEe, 256, 0, stream>>>(H0, ptrC, cntC, entC, Ee);
  k_fillC<<<gEe, 256, 0, stream>>>(H1, ptrC, cntC, entC, Ee);

  // ---- CSR D: raw graph by dst (N segments, E entries, value = src) ----
  hipMemsetAsync(cntD, 0, (size_t)Nn * 4, stream);
  k_count_direct<<<gEe, 256, 0, stream>>>(dst, cntD, Ee);
  scan(cntD, ptrD, Nn, Ee);
  hipMemsetAsync(cntD, 0, (size_t)Nn * 4, stream);
  k_fillD<<<gEe, 256, 0, stream>>>(dst, src, ptrD, cntD, entD, Ee);
  k_rdeg<<<cdiv(Nn, 256), 256, 0, stream>>>(ptrC, rdegN, Nn);

  const int gN128 = cdiv(Nn, 128);                      // 391
  const int gW    = cdiv(Nn, 4);                        // 12500
  const int gP2   = cdiv(cdiv(2 * LGEe, 256), 4);       // 3125
  const int gP1   = cdiv(cdiv(2 * Ee, 256), 4);         // 1563
  const int gPf   = cdiv(cdiv(Ee, 256), 4);             // 782

  // ---- TSA layer 1, fused self+nbr -> BUF (bf16, pre-relu), split-bf16 MFMA ----
  k_tsa1<<<Ee / 64, 256, 0, stream>>>(et, ptrA, entA, W_tsa1_s, W_tsa1_n, BUF);

  // ---- TSA layer 2 + EdgeToNode via balanced chunked pooling ----
  // pool2 (composed nbr term) -> agg; T = agg @ W2n   (entBs/entBw die here)
  hipMemsetAsync(agg, 0, NH * 4, stream);
  k_poolb<<<gP2, 256, 0, stream>>>(ptrB, entBs, entBw, BUF, agg, Nn, 2 * LGEe);
  k_gemm128<<<gN128, 256, 0, stream>>>(Nn, agg, 128, W_tsa2_n, nullptr, 0, 0, T, 0);
  // pool1 (self term over incidence) -> agg; T += agg @ W2s   (BUF dies here)
  hipMemsetAsync(agg, 0, NH * 4, stream);
  k_poolb<<<gP1, 256, 0, stream>>>(ptrC, entC, nullptr, BUF, agg, Nn, 2 * Ee);
  k_gemm128<<<gN128, 256, 0, stream>>>(Nn, agg, 128, W_tsa2_s, nullptr, 0, 0, T, 1);
  // node_e = leaky(rdeg * T @ W_etn); er = node_e @ W_eg_lin
  k_gemm128<<<gN128, 256, 0, stream>>>(Nn, T, 128, W_etn, rdegN, 0, 2, tmp, 0);
  k_gemm128<<<gN128, 256, 0, stream>>>(Nn, tmp, 128, W_eg_lin, nullptr, 0, 0, er, 0);

  // ---- edge_aggr SAGE ----
  k_gemm128<<<gN128, 256, 0, stream>>>(Nn, er, 128, W_ea_s, nullptr, 0, 0, ae, 0);
  k_gemm128<<<gN128, 256, 0, stream>>>(Nn, er, 128, W_ea_n, nullptr, 0, 0, tmp, 0);
  k_poolf<<<gPf, 256, 0, stream>>>(ptrD, entD, tmp, ae, Nn, Ee);

  // ---- attr_node_model (hn kept pre-relu; relu applied on read) ----
  k_gemm128<<<gN128, 256, 0, stream>>>(Nn, x, 256, W_an1_s, nullptr, 0, 0, hn, 0);
  k_gemm128<<<gN128, 256, 0, stream>>>(Nn, x, 256, W_an1_n, nullptr, 0, 0, tmp, 0);
  k_poolf<<<gPf, 256, 0, stream>>>(ptrD, entD, tmp, hn, Nn, Ee);
  k_gemm128<<<gN128, 256, 0, stream>>>(Nn, hn, 128, W_an2_s, nullptr, 1, 0, hn2, 0);
  k_gemm128<<<gN128, 256, 0, stream>>>(Nn, hn, 128, W_an2_n, nullptr, 1, 0, tmp, 0);
  k_poolf<<<gPf, 256, 0, stream>>>(ptrD, entD, tmp, hn2, Nn, Ee);

  // ---- MixAttention (fused online softmax; out accumulated into hn2) ----
  k_gemm128<<<gN128, 256, 0, stream>>>(Nn, hn2, 128, Wq, nullptr, 0, 0, qb, 0);
  k_gemm128<<<gN128, 256, 0, stream>>>(Nn, ae, 128, Wk, nullptr, 0, 0, kb, 0);
  k_gemm128<<<gN128, 256, 0, stream>>>(Nn, ae, 128, Wv, nullptr, 0, 0, vb, 0);
  k_attn<<<gW, 256, 0, stream>>>(ptrD, entD, qb, kb, vb, hn2, Nn);

  // ---- classifier + log_softmax ----
  k_out<<<gW, 256, 0, stream>>>(hn2, W_out, out, Nn);
}

// Round 6
// 2302.205 us; speedup vs baseline: 1.6096x; 1.2214x over previous
//
#include <hip/hip_runtime.h>
#include <cstddef>

static constexpr int Nn   = 50000;
static constexpr int Ee   = 800000;
static constexpr int LGEe = 1600000;

typedef __attribute__((ext_vector_type(8))) short bf16x8;
typedef __attribute__((ext_vector_type(4))) float f32x4;

__device__ __forceinline__ float bf2f(unsigned int u16) {
  return __uint_as_float(u16 << 16);
}
__device__ __forceinline__ unsigned int f2bf(float f) {
  unsigned int u = __float_as_uint(f);
  u += 0x7fffu + ((u >> 16) & 1u);   // RNE
  return u >> 16;
}

// ---------------- CSR build kernels ----------------
__global__ __launch_bounds__(256)
void k_count_direct(const int* __restrict__ idx, int* __restrict__ cnt, int n) {
  int i = blockIdx.x * 256 + threadIdx.x;
  if (i < n) atomicAdd(&cnt[idx[i]], 1);
}
__global__ __launch_bounds__(256)
void k_count_comp(const int* __restrict__ Hrow, const int* __restrict__ dlg,
                  int* __restrict__ cnt, int n) {
  int i = blockIdx.x * 256 + threadIdx.x;
  if (i < n) atomicAdd(&cnt[Hrow[dlg[i]]], 1);
}
__global__ __launch_bounds__(256)
void k_scan1(const int* __restrict__ in, int* __restrict__ out,
             int* __restrict__ bsum, int n) {
  __shared__ int sd[256];
  int tid = threadIdx.x;
  int base = blockIdx.x * 1024 + tid * 4;
  int4 v = {0, 0, 0, 0};
  if (base < n) v = *(const int4*)(in + base);   // n % 4 == 0 for all uses
  int s = v.x + v.y + v.z + v.w;
  sd[tid] = s; __syncthreads();
  for (int off = 1; off < 256; off <<= 1) {
    int t_ = (tid >= off) ? sd[tid - off] : 0; __syncthreads();
    sd[tid] += t_; __syncthreads();
  }
  int excl = sd[tid] - s;
  if (base < n) {
    int4 o; o.x = excl; o.y = o.x + v.x; o.z = o.y + v.y; o.w = o.z + v.z;
    *(int4*)(out + base) = o;
  }
  if (tid == 255) bsum[blockIdx.x] = sd[255];
}
__global__ __launch_bounds__(1024)
void k_scan2(int* __restrict__ b, int nb) {
  __shared__ int sd[1024];
  int tid = threadIdx.x;
  int v = (tid < nb) ? b[tid] : 0;
  sd[tid] = v; __syncthreads();
  for (int off = 1; off < 1024; off <<= 1) {
    int t_ = (tid >= off) ? sd[tid - off] : 0; __syncthreads();
    sd[tid] += t_; __syncthreads();
  }
  if (tid < nb) b[tid] = sd[tid] - v;
}
__global__ __launch_bounds__(256)
void k_scan3(int* __restrict__ out, const int* __restrict__ bsum, int n, int total) {
  int i = blockIdx.x * 256 + threadIdx.x;
  if (i < n) out[i] += bsum[i >> 10];
  if (i == 0) out[n] = total;
}
__global__ __launch_bounds__(256)
void k_fillA(const int* __restrict__ dlg, const int* __restrict__ slg,
             const int* __restrict__ ptr, int* __restrict__ cur,
             int* __restrict__ ent, int n) {
  int m = blockIdx.x * 256 + threadIdx.x;
  if (m >= n) return;
  int d = dlg[m];
  int pos = ptr[d] + atomicAdd(&cur[d], 1);
  ent[pos] = slg[m];
}
__global__ __launch_bounds__(256)
void k_fillB(const int* __restrict__ Hrow, const int* __restrict__ dlg,
             const int* __restrict__ slg, const int* __restrict__ ptrA,
             const int* __restrict__ ptrB, int* __restrict__ cur,
             int* __restrict__ entS, float* __restrict__ entW, int n) {
  int m = blockIdx.x * 256 + threadIdx.x;
  if (m >= n) return;
  int d = dlg[m];
  int seg = Hrow[d];
  int pos = ptrB[seg] + atomicAdd(&cur[seg], 1);
  entS[pos] = slg[m];
  int la = ptrA[d + 1] - ptrA[d];
  entW[pos] = 1.0f / (float)max(la, 1);
}
__global__ __launch_bounds__(256)
void k_fillC(const int* __restrict__ Hrow, const int* __restrict__ ptr,
             int* __restrict__ cur, int* __restrict__ ent, int n) {
  int e = blockIdx.x * 256 + threadIdx.x;
  if (e >= n) return;
  int seg = Hrow[e];
  int pos = ptr[seg] + atomicAdd(&cur[seg], 1);
  ent[pos] = e;
}
__global__ __launch_bounds__(256)
void k_fillD(const int* __restrict__ dstA, const int* __restrict__ srcA,
             const int* __restrict__ ptr, int* __restrict__ cur,
             int* __restrict__ ent, int n) {
  int e = blockIdx.x * 256 + threadIdx.x;
  if (e >= n) return;
  int seg = dstA[e];
  int pos = ptr[seg] + atomicAdd(&cur[seg], 1);
  ent[pos] = srcA[e];
}
__global__ __launch_bounds__(256)
void k_rdeg(const int* __restrict__ ptr, float* __restrict__ r, int n) {
  int i = blockIdx.x * 256 + threadIdx.x;
  if (i < n) r[i] = 1.0f / fmaxf((float)(ptr[i + 1] - ptr[i]), 1.0f);
}

// ---------------- dense MFMA GEMM (split-bf16), 64-row tile ----------------
// C1 = act( rowmul(reluA(A)) @ W1 ) (+beta1*C1); if DUAL: C2 = act( ... @ W2 ).
// A staged once in LDS hi/lo bf16 (tsa1-verified swizzle); W frags per-lane
// from global; 3-term split product per tile. K in {128, 256}.
#define MG_SWEEP(WP, ACC)                                                       \
  {                                                                             \
    bf16x8 Bh[2][4], Bl[2][4];                                                  \
    _Pragma("unroll")                                                           \
    for (int np = 0; np < 2; ++np) {                                            \
      int n = (wv * 2 + np) * 16 + nrow;                                        \
      _Pragma("unroll")                                                         \
      for (int kc = 0; kc < 4; ++kc) {                                          \
        int kr0 = kh * 128 + kc * 32 + kg * 8;                                  \
        _Pragma("unroll")                                                       \
        for (int j = 0; j < 8; ++j) {                                           \
          float w = (WP)[(size_t)(kr0 + j) * 128 + n];                          \
          unsigned int hi = f2bf(w);                                            \
          float lo = w - bf2f(hi);                                              \
          Bh[np][kc][j] = (short)(unsigned short)hi;                            \
          Bl[np][kc][j] = (short)(unsigned short)f2bf(lo);                      \
        }                                                                       \
      }                                                                         \
    }                                                                           \
    _Pragma("unroll")                                                           \
    for (int kc = 0; kc < 4; ++kc) {                                            \
      _Pragma("unroll")                                                         \
      for (int m = 0; m < 4; ++m) {                                             \
        int ss = m * 16 + nrow;                                                 \
        int idx = ss * 128 + ((kc * 32 + kg * 8) ^ ((ss & 7) << 3));            \
        bf16x8 ah = *(const bf16x8*)(sAh + idx);                                \
        bf16x8 al = *(const bf16x8*)(sAl + idx);                                \
        _Pragma("unroll")                                                       \
        for (int np = 0; np < 2; ++np) {                                        \
          ACC[m][np] = __builtin_amdgcn_mfma_f32_16x16x32_bf16(ah, Bh[np][kc], ACC[m][np], 0, 0, 0); \
          ACC[m][np] = __builtin_amdgcn_mfma_f32_16x16x32_bf16(al, Bh[np][kc], ACC[m][np], 0, 0, 0); \
          ACC[m][np] = __builtin_amdgcn_mfma_f32_16x16x32_bf16(ah, Bl[np][kc], ACC[m][np], 0, 0, 0); \
        }                                                                       \
      }                                                                         \
    }                                                                           \
  }

template <int DUAL>
__global__ __launch_bounds__(256)
void k_mgemm(int M, const float* __restrict__ A, int K,
             const float* __restrict__ W1, const float* __restrict__ W2,
             const float* __restrict__ dgA, int reluA, int act,
             float* __restrict__ C1, float* __restrict__ C2, int beta1)
{
  __shared__ __align__(16) unsigned char smem[34816];
  unsigned short* sAh = (unsigned short*)smem;            // [64][128] bf16 hi
  unsigned short* sAl = (unsigned short*)(smem + 16384);  // [64][128] bf16 lo
  float* stage = (float*)smem;                            // [64][132] f32 epilogue

  const int t = threadIdx.x, wv = t >> 6, lane = t & 63;
  const int tr = t >> 4, tc = t & 15;
  const int nrow = lane & 15, kg = lane >> 4;
  const int row0 = blockIdx.x * 64;

  f32x4 acc1[4][2], acc2[4][2];
  #pragma unroll
  for (int m = 0; m < 4; ++m)
    #pragma unroll
    for (int np = 0; np < 2; ++np) {
      acc1[m][np] = (f32x4){0.f, 0.f, 0.f, 0.f};
      if (DUAL) acc2[m][np] = (f32x4){0.f, 0.f, 0.f, 0.f};
    }

  const int nkh = K >> 7;
  #pragma unroll 1
  for (int kh = 0; kh < nkh; ++kh) {
    if (kh) __syncthreads();           // sA reads of previous half done
    // ---- stage A[64][128] half as split hi/lo bf16 (swizzled, coalesced) ----
    #pragma unroll
    for (int j = 0; j < 8; ++j) {
      int idx = t + j * 256;           // float4 id, 0..2047
      int r = idx >> 5, c4 = idx & 31;
      int gr = row0 + r; if (gr > M - 1) gr = M - 1;
      float4 va = *(const float4*)(A + (size_t)gr * K + kh * 128 + c4 * 4);
      if (reluA) {
        va.x = fmaxf(va.x, 0.f); va.y = fmaxf(va.y, 0.f);
        va.z = fmaxf(va.z, 0.f); va.w = fmaxf(va.w, 0.f);
      }
      if (dgA) {
        float sc = dgA[gr];
        va.x *= sc; va.y *= sc; va.z *= sc; va.w *= sc;
      }
      float v[4] = {va.x, va.y, va.z, va.w};
      unsigned int h[4], l[4];
      #pragma unroll
      for (int q = 0; q < 4; ++q) {
        h[q] = f2bf(v[q]);
        l[q] = f2bf(v[q] - bf2f(h[q]));
      }
      int bidx = r * 128 + ((c4 * 4) ^ ((r & 7) << 3));
      uint2 ph = {h[0] | (h[1] << 16), h[2] | (h[3] << 16)};
      uint2 pl = {l[0] | (l[1] << 16), l[2] | (l[3] << 16)};
      *(uint2*)(sAh + bidx) = ph;
      *(uint2*)(sAl + bidx) = pl;
    }
    __syncthreads();

    MG_SWEEP(W1, acc1);
    if (DUAL) MG_SWEEP(W2, acc2);
  }

  // ---- epilogue: frag (col=lane&15, row=kg*4+r) -> f32 stage -> float4 ----
  __syncthreads();
  #pragma unroll
  for (int m = 0; m < 4; ++m)
    #pragma unroll
    for (int np = 0; np < 2; ++np)
      #pragma unroll
      for (int r = 0; r < 4; ++r)
        stage[(m * 16 + kg * 4 + r) * 132 + (wv * 2 + np) * 16 + nrow] = acc1[m][np][r];
  __syncthreads();
  #pragma unroll
  for (int i = 0; i < 4; ++i) {
    int s = tr * 4 + i, gr = row0 + s;
    if (gr >= M) continue;
    const float* sp = stage + s * 132 + tc * 8;
    float4 v0 = *(const float4*)sp, v1 = *(const float4*)(sp + 4);
    float o[8] = {v0.x, v0.y, v0.z, v0.w, v1.x, v1.y, v1.z, v1.w};
    #pragma unroll
    for (int j2 = 0; j2 < 8; ++j2) {
      float vv = o[j2];
      if (act == 1)      vv = fmaxf(vv, 0.f);
      else if (act == 2) vv = vv > 0.f ? vv : 0.2f * vv;
      o[j2] = vv;
    }
    float* p = C1 + (size_t)gr * 128 + tc * 8;
    if (beta1) {
      float4 c0 = *(const float4*)p, c1 = *(const float4*)(p + 4);
      o[0] += c0.x; o[1] += c0.y; o[2] += c0.z; o[3] += c0.w;
      o[4] += c1.x; o[5] += c1.y; o[6] += c1.z; o[7] += c1.w;
    }
    *(float4*)p       = *(const float4*)&o[0];
    *(float4*)(p + 4) = *(const float4*)&o[4];
  }
  if (DUAL) {
    __syncthreads();
    #pragma unroll
    for (int m = 0; m < 4; ++m)
      #pragma unroll
      for (int np = 0; np < 2; ++np)
        #pragma unroll
        for (int r = 0; r < 4; ++r)
          stage[(m * 16 + kg * 4 + r) * 132 + (wv * 2 + np) * 16 + nrow] = acc2[m][np][r];
    __syncthreads();
    #pragma unroll
    for (int i = 0; i < 4; ++i) {
      int s = tr * 4 + i, gr = row0 + s;
      if (gr >= M) continue;
      const float* sp = stage + s * 132 + tc * 8;
      float4 v0 = *(const float4*)sp, v1 = *(const float4*)(sp + 4);
      float o[8] = {v0.x, v0.y, v0.z, v0.w, v1.x, v1.y, v1.z, v1.w};
      #pragma unroll
      for (int j2 = 0; j2 < 8; ++j2) {
        float vv = o[j2];
        if (act == 1)      vv = fmaxf(vv, 0.f);
        else if (act == 2) vv = vv > 0.f ? vv : 0.2f * vv;
        o[j2] = vv;
      }
      float* p = C2 + (size_t)gr * 128 + tc * 8;
      *(float4*)p       = *(const float4*)&o[0];
      *(float4*)(p + 4) = *(const float4*)&o[4];
    }
  }
}

// ---------------- fused TSA1 (split-bf16 MFMA): ----------------
// BUF[e] = bf16( et[e]@Ws + mean_{s in A(e)} et[s] @ Wn ), 64 segs/block.
__global__ __launch_bounds__(256)
void k_tsa1(const float* __restrict__ et,
            const int* __restrict__ rp, const int* __restrict__ ent,
            const float* __restrict__ Ws, const float* __restrict__ Wn,
            unsigned short* __restrict__ BUF)
{
  __shared__ __align__(16) unsigned char smem[34816];
  unsigned short* sAh = (unsigned short*)smem;            // [64][128] bf16 hi
  unsigned short* sAl = (unsigned short*)(smem + 16384);  // [64][128] bf16 lo
  int*   sEnt  = (int*)(smem + 32768);                    // 512 ints
  float* stage = (float*)smem;                            // [64][132] f32 (epilogue)

  const int t = threadIdx.x, wv = t >> 6, lane = t & 63;
  const int tr = t >> 4, tc = t & 15;
  const int nrow = lane & 15, kg = lane >> 4;
  const int seg0 = blockIdx.x * 64;
  const int segbase = seg0 + wv * 16;

  // lanes 0..16 hold row pointers of this wave's 16 segments
  int rpv = (lane <= 16) ? rp[segbase + lane] : 0;
  int nxtv = __shfl(rpv, (lane + 1) & 63);
  float invv = 1.f / fmaxf((float)(nxtv - rpv), 1.f);   // valid lanes 0..15

  // cache block's contiguous ent slice (coalesced); >512 falls back to global
  const int base = rp[seg0];
  const int cnt  = rp[seg0 + 64] - base;
  const int lim  = cnt < 512 ? cnt : 512;
  for (int i = t; i < lim; i += 256) sEnt[i] = ent[base + i];

  // direct half (k = lane): coalesced loads, split hi/lo, swizzled b16 writes
  {
    float dv[16];
    #pragma unroll
    for (int i = 0; i < 16; ++i)
      dv[i] = et[(size_t)(segbase + i) * 64 + lane];
    #pragma unroll
    for (int i = 0; i < 16; ++i) {
      int ss = wv * 16 + i;
      unsigned int hi = f2bf(dv[i]);
      float lo = dv[i] - bf2f(hi);
      int idx = ss * 128 + (lane ^ ((ss & 7) << 3));
      sAh[idx] = (unsigned short)hi;
      sAl[idx] = (unsigned short)f2bf(lo);
    }
  }

  // B fragments from global (W is L2-resident): lane supplies
  // B[k = kg*8+j][n = ntile*16 + nrow] for its wave's 2 n-tiles x 4 k-chunks.
  bf16x8 Bh[2][4], Bl[2][4];
  #pragma unroll
  for (int np = 0; np < 2; ++np) {
    int n = (wv * 2 + np) * 16 + nrow;
    #pragma unroll
    for (int kc = 0; kc < 4; ++kc) {
      const float* Wp = (kc < 2) ? Ws : Wn;
      int kr0 = (kc & 1) * 32 + kg * 8;
      #pragma unroll
      for (int j = 0; j < 8; ++j) {
        float w = Wp[(size_t)(kr0 + j) * 128 + n];
        unsigned int hi = f2bf(w);
        float lo = w - bf2f(hi);
        Bh[np][kc][j] = (short)(unsigned short)hi;
        Bl[np][kc][j] = (short)(unsigned short)f2bf(lo);
      }
    }
  }
  __syncthreads();   // sEnt ready

  // gathered half (k = 64+lane): flatten over entries, 8 row-loads in flight
  {
    int q0 = __shfl(rpv, 0);
    int q1 = __shfl(rpv, 16);
    int c = 0;
    int b_next = __shfl(rpv, 1);
    float idg = __shfl(invv, 0);
    float a = 0.f;
    #pragma unroll 1
    for (int j = q0; j < q1; j += 8) {
      float x[8];
      #pragma unroll
      for (int u = 0; u < 8; ++u) {
        int jj = j + u; jj = jj < q1 ? jj : q1 - 1;
        int ix = jj - base;
        int s = (ix < 512) ? sEnt[ix] : ent[jj];
        x[u] = et[(size_t)s * 64 + lane];
      }
      #pragma unroll
      for (int u = 0; u < 8; ++u) {
        int jj = j + u;
        if (jj >= q1) break;
        while (jj >= b_next) {        // column c complete -> flush
          float v = a * idg;
          int ss = wv * 16 + c;
          unsigned int hi = f2bf(v);
          float lo = v - bf2f(hi);
          int idx = ss * 128 + ((64 + lane) ^ ((ss & 7) << 3));
          sAh[idx] = (unsigned short)hi;
          sAl[idx] = (unsigned short)f2bf(lo);
          a = 0.f;
          ++c;
          b_next = __shfl(rpv, c + 1);
          idg = __shfl(invv, c);
        }
        a += x[u];
      }
    }
    #pragma unroll 1
    for (;;) {                        // flush current + trailing columns
      float v = a * idg;
      int ss = wv * 16 + c;
      unsigned int hi = f2bf(v);
      float lo = v - bf2f(hi);
      int idx = ss * 128 + ((64 + lane) ^ ((ss & 7) << 3));
      sAh[idx] = (unsigned short)hi;
      sAl[idx] = (unsigned short)f2bf(lo);
      a = 0.f;
      if (++c >= 16) break;
      idg = __shfl(invv, c);
    }
  }
  __syncthreads();

  // MFMA: out[64 seg][128 feat], split product Ah*Bh + Al*Bh + Ah*Bl
  f32x4 acc[4][2];
  #pragma unroll
  for (int m = 0; m < 4; ++m)
    #pragma unroll
    for (int np = 0; np < 2; ++np)
      acc[m][np] = (f32x4){0.f, 0.f, 0.f, 0.f};

  #pragma unroll
  for (int kc = 0; kc < 4; ++kc) {
    #pragma unroll
    for (int m = 0; m < 4; ++m) {
      int ss = m * 16 + nrow;
      int kbase = kc * 32 + kg * 8;
      int idx = ss * 128 + (kbase ^ ((ss & 7) << 3));
      bf16x8 ah = *(const bf16x8*)(sAh + idx);
      bf16x8 al = *(const bf16x8*)(sAl + idx);
      #pragma unroll
      for (int np = 0; np < 2; ++np) {
        acc[m][np] = __builtin_amdgcn_mfma_f32_16x16x32_bf16(ah, Bh[np][kc], acc[m][np], 0, 0, 0);
        acc[m][np] = __builtin_amdgcn_mfma_f32_16x16x32_bf16(al, Bh[np][kc], acc[m][np], 0, 0, 0);
        acc[m][np] = __builtin_amdgcn_mfma_f32_16x16x32_bf16(ah, Bl[np][kc], acc[m][np], 0, 0, 0);
      }
    }
  }

  // epilogue: C/D frag (col=lane&15, row=(lane>>4)*4+r) -> f32 stage -> uint4
  __syncthreads();
  #pragma unroll
  for (int m = 0; m < 4; ++m)
    #pragma unroll
    for (int np = 0; np < 2; ++np)
      #pragma unroll
      for (int r = 0; r < 4; ++r)
        stage[(m * 16 + kg * 4 + r) * 132 + (wv * 2 + np) * 16 + nrow] = acc[m][np][r];
  __syncthreads();
  #pragma unroll
  for (int i = 0; i < 4; ++i) {
    int s = tr * 4 + i;
    const float* sp = stage + s * 132 + tc * 8;
    float4 v0 = *(const float4*)sp;
    float4 v1 = *(const float4*)(sp + 4);
    unsigned int pk[4];
    pk[0] = f2bf(v0.x) | (f2bf(v0.y) << 16);
    pk[1] = f2bf(v0.z) | (f2bf(v0.w) << 16);
    pk[2] = f2bf(v1.x) | (f2bf(v1.y) << 16);
    pk[3] = f2bf(v1.z) | (f2bf(v1.w) << 16);
    uint4 st = {pk[0], pk[1], pk[2], pk[3]};
    *(uint4*)(BUF + (size_t)(seg0 + s) * 128 + tc * 8) = st;
  }
}

// ---------------- balanced chunked pooling (bf16 rows, relu, opt weights) ----
__global__ __launch_bounds__(256)
void k_poolb(const int* __restrict__ rp, const int* __restrict__ ent,
             const float* __restrict__ entw,
             const unsigned short* __restrict__ SRC,
             float* __restrict__ O, int nseg, int total)
{
  const int wv = threadIdx.x >> 6, lane = threadIdx.x & 63;
  const int chunk = blockIdx.x * 4 + wv;
  const int c0 = chunk * 256;
  if (c0 >= total) return;
  int c1 = c0 + 256; if (c1 > total) c1 = total;

  int lo = 0, hi = nseg;                 // rp[lo] <= c0 < rp[hi]
  while (lo + 1 < hi) {
    int mid = (lo + hi) >> 1;
    if (rp[mid] <= c0) lo = mid; else hi = mid;
  }
  int seg = lo;
  int sstart = rp[seg];
  int send = rp[seg + 1];
  float a0 = 0.f, a1 = 0.f;

  #pragma unroll 1
  for (int j = c0; j < c1; j += 8) {
    int ids[8]; float w[8];
    #pragma unroll
    for (int u = 0; u < 8; ++u) {
      int jj = j + u; jj = jj < c1 ? jj : c1 - 1;
      ids[u] = ent[jj];
      w[u] = entw ? entw[jj] : 1.f;
    }
    unsigned int uv[8];
    #pragma unroll
    for (int u = 0; u < 8; ++u)
      uv[u] = *(const unsigned int*)(SRC + (size_t)ids[u] * 128 + 2 * lane);
    #pragma unroll
    for (int u = 0; u < 8; ++u) {
      int jj = j + u;
      if (jj >= c1) break;
      while (jj >= send) {               // segment complete -> flush
        float* p = O + (size_t)seg * 128;
        if (sstart >= c0 && send <= c1) {
          p[2 * lane]     += a0;
          p[2 * lane + 1] += a1;
        } else {
          atomicAdd(p + 2 * lane, a0);
          atomicAdd(p + 2 * lane + 1, a1);
        }
        a0 = a1 = 0.f;
        ++seg; sstart = send; send = rp[seg + 1];
      }
      a0 = fmaf(w[u], fmaxf(bf2f(uv[u] & 0xffffu), 0.f), a0);
      a1 = fmaf(w[u], fmaxf(bf2f(uv[u] >> 16),     0.f), a1);
    }
  }
  {                                       // final flush (possibly partial seg)
    float* p = O + (size_t)seg * 128;
    if (sstart >= c0 && send <= c1) {
      p[2 * lane]     += a0;
      p[2 * lane + 1] += a1;
    } else {
      atomicAdd(p + 2 * lane, a0);
      atomicAdd(p + 2 * lane + 1, a1);
    }
  }
}

// ---------------- balanced chunked segment-mean (f32 rows): O[seg] += mean ----
__global__ __launch_bounds__(256)
void k_poolf(const int* __restrict__ rp, const int* __restrict__ ent,
             const float* __restrict__ SRC, float* __restrict__ O,
             int nseg, int total)
{
  const int wv = threadIdx.x >> 6, lane = threadIdx.x & 63;
  const int chunk = blockIdx.x * 4 + wv;
  const int c0 = chunk * 256;
  if (c0 >= total) return;
  int c1 = c0 + 256; if (c1 > total) c1 = total;

  int lo = 0, hi = nseg;
  while (lo + 1 < hi) {
    int mid = (lo + hi) >> 1;
    if (rp[mid] <= c0) lo = mid; else hi = mid;
  }
  int seg = lo;
  int sstart = rp[seg];
  int send = rp[seg + 1];
  float a0 = 0.f, a1 = 0.f;

  #pragma unroll 1
  for (int j = c0; j < c1; j += 8) {
    int ids[8];
    #pragma unroll
    for (int u = 0; u < 8; ++u) {
      int jj = j + u; jj = jj < c1 ? jj : c1 - 1;
      ids[u] = ent[jj];
    }
    float2 v[8];
    #pragma unroll
    for (int u = 0; u < 8; ++u)
      v[u] = ((const float2*)(SRC + (size_t)ids[u] * 128))[lane];
    #pragma unroll
    for (int u = 0; u < 8; ++u) {
      int jj = j + u;
      if (jj >= c1) break;
      while (jj >= send) {               // segment complete -> flush mean
        float sc = 1.f / fmaxf((float)(send - sstart), 1.f);
        float* p = O + (size_t)seg * 128;
        if (sstart >= c0 && send <= c1) {
          p[2 * lane]     += a0 * sc;
          p[2 * lane + 1] += a1 * sc;
        } else {
          atomicAdd(p + 2 * lane, a0 * sc);
          atomicAdd(p + 2 * lane + 1, a1 * sc);
        }
        a0 = a1 = 0.f;
        ++seg; sstart = send; send = rp[seg + 1];
      }
      a0 += v[u].x; a1 += v[u].y;
    }
  }
  {
    float sc = 1.f / fmaxf((float)(send - sstart), 1.f);
    float* p = O + (size_t)seg * 128;
    if (sstart >= c0 && send <= c1) {
      p[2 * lane]     += a0 * sc;
      p[2 * lane + 1] += a1 * sc;
    } else {
      atomicAdd(p + 2 * lane, a0 * sc);
      atomicAdd(p + 2 * lane + 1, a1 * sc);
    }
  }
}

// ---------------- fused attention: online softmax + PV, one wave per node ----------------
__global__ __launch_bounds__(256)
void k_attn(const int* __restrict__ rp, const int* __restrict__ ent,
            const float* __restrict__ q, const float* __restrict__ kb,
            const float* __restrict__ vb, float* __restrict__ o, int nseg)
{
  int wv = threadIdx.x >> 6, lane = threadIdx.x & 63;
  int seg = blockIdx.x * 4 + wv;
  if (seg >= nseg) return;
  int p0 = rp[seg], p1 = rp[seg + 1];
  if (p0 >= p1) return;
  float2 q2 = ((const float2*)(q + (size_t)seg * 128))[lane];
  float m = -1e30f, l = 0.f, o0 = 0.f, o1 = 0.f;
  #pragma unroll 1
  for (int j = p0; j < p1; j += 4) {
    int s[4];
    #pragma unroll
    for (int i = 0; i < 4; ++i) {
      int jj = j + i; jj = jj < p1 ? jj : p1 - 1;
      s[i] = ent[jj];
    }
    float2 k2[4], v2[4];
    #pragma unroll
    for (int i = 0; i < 4; ++i)
      k2[i] = ((const float2*)(kb + (size_t)s[i] * 128))[lane];
    #pragma unroll
    for (int i = 0; i < 4; ++i)
      v2[i] = ((const float2*)(vb + (size_t)s[i] * 128))[lane];
    float d[4];
    #pragma unroll
    for (int i = 0; i < 4; ++i) d[i] = fmaf(q2.x, k2[i].x, q2.y * k2[i].y);
    #pragma unroll
    for (int off = 1; off < 64; off <<= 1) {
      #pragma unroll
      for (int i = 0; i < 4; ++i) d[i] += __shfl_xor(d[i], off);
    }
    float sc[4];
    #pragma unroll
    for (int i = 0; i < 4; ++i) {
      float v = d[i] * 0.088388347648318447f;      // 1/sqrt(128)
      v = v > 0.f ? v : 0.2f * v;                  // leaky 0.2
      sc[i] = (j + i < p1) ? v : -1e30f;
    }
    float mb = fmaxf(fmaxf(sc[0], sc[1]), fmaxf(sc[2], sc[3]));
    float mn = fmaxf(m, mb);
    float scale = expf(m - mn);
    float e[4];
    #pragma unroll
    for (int i = 0; i < 4; ++i)
      e[i] = (j + i < p1) ? expf(sc[i] - mn) : 0.f;
    l  = l  * scale + ((e[0] + e[1]) + (e[2] + e[3]));
    o0 = o0 * scale + ((e[0] * v2[0].x + e[1] * v2[1].x) + (e[2] * v2[2].x + e[3] * v2[3].x));
    o1 = o1 * scale + ((e[0] * v2[0].y + e[1] * v2[1].y) + (e[2] * v2[2].y + e[3] * v2[3].y));
    m = mn;
  }
  float inv = 1.f / fmaxf(l, 1e-9f);
  float2* orow = (float2*)(o + (size_t)seg * 128);
  float2 cur = orow[lane];
  cur.x += o0 * inv; cur.y += o1 * inv;
  orow[lane] = cur;
}

// ---------------- classifier + log_softmax ----------------
__global__ __launch_bounds__(256)
void k_out(const float* __restrict__ attn, const float* __restrict__ Wout,
           float* __restrict__ out, int n) {
  __shared__ float sW[128 * 64];
  for (int i = threadIdx.x; i < 128 * 64; i += 256) sW[i] = Wout[i];
  __syncthreads();
  int wave = threadIdx.x >> 6, lane = threadIdx.x & 63;
  int row = blockIdx.x * 4 + wave;
  if (row >= n) return;
  const float* a = attn + (size_t)row * 128;
  float z = 0.f;
  #pragma unroll 8
  for (int k = 0; k < 128; ++k) z = fmaf(a[k], sW[k * 64 + lane], z);
  float mx = z;
  #pragma unroll
  for (int off = 32; off; off >>= 1) mx = fmaxf(mx, __shfl_xor(mx, off));
  float ee = expf(z - mx);
  float ss = ee;
  #pragma unroll
  for (int off = 32; off; off >>= 1) ss += __shfl_xor(ss, off);
  out[(size_t)row * 64 + lane] = z - mx - logf(ss);
}

extern "C" void kernel_launch(void* const* d_in, const int* in_sizes, int n_in,
                              void* d_out, int out_size, void* d_ws, size_t ws_size,
                              hipStream_t stream) {
  (void)in_sizes; (void)n_in; (void)out_size;
  const float* x        = (const float*)d_in[0];
  const float* et       = (const float*)d_in[1];
  const int*   H0       = (const int*)d_in[2];
  const int*   H1       = H0 + Ee;
  const int*   src      = (const int*)d_in[3];
  const int*   dst      = src + Ee;
  const int*   src_lg   = (const int*)d_in[4];
  const int*   dst_lg   = src_lg + LGEe;
  const float* W_tsa1_s = (const float*)d_in[5];
  const float* W_tsa1_n = (const float*)d_in[6];
  const float* W_tsa2_s = (const float*)d_in[7];
  const float* W_tsa2_n = (const float*)d_in[8];
  const float* W_etn    = (const float*)d_in[9];
  const float* W_eg_lin = (const float*)d_in[10];
  const float* W_ea_s   = (const float*)d_in[11];
  const float* W_ea_n   = (const float*)d_in[12];
  const float* W_an1_s  = (const float*)d_in[13];
  const float* W_an1_n  = (const float*)d_in[14];
  const float* W_an2_s  = (const float*)d_in[15];
  const float* W_an2_n  = (const float*)d_in[16];
  const float* Wq       = (const float*)d_in[17];
  const float* Wk       = (const float*)d_in[18];
  const float* Wv       = (const float*)d_in[19];
  const float* W_out    = (const float*)d_in[20];
  float* out = (float*)d_out;

  // ---- workspace carve ----
  char* wp = (char*)d_ws;
  size_t avail = ws_size;
  auto alloc = [&](size_t bytes) -> void* {
    void* r = (void*)wp;
    size_t pad = (bytes + 255) & ~(size_t)255;
    wp += pad; avail = (avail >= pad) ? avail - pad : 0;
    return r;
  };
  const size_t NH = (size_t)Nn * 128;
  unsigned short* BUF = (unsigned short*)alloc((size_t)Ee * 128 * 2); // 204.8MB bf16 h1
  float* agg   = (float*)alloc(NH * 4);
  int* ptrA  = (int*)alloc(((size_t)Ee + 1) * 4);
  int* cntA  = (int*)alloc((size_t)Ee * 4);
  int* entA  = (int*)alloc((size_t)LGEe * 4);
  int* ptrB  = (int*)alloc(((size_t)Nn + 1) * 4);
  int* cntB  = (int*)alloc((size_t)Nn * 4);
  int* entBs = (int*)alloc((size_t)2 * LGEe * 4);
  float* entBw = (float*)alloc((size_t)2 * LGEe * 4);
  int* ptrC  = (int*)alloc(((size_t)Nn + 1) * 4);
  int* cntC  = (int*)alloc((size_t)Nn * 4);
  int* entC  = (int*)alloc((size_t)2 * Ee * 4);
  int* ptrD  = (int*)alloc(((size_t)Nn + 1) * 4);
  int* cntD  = (int*)alloc((size_t)Nn * 4);
  int* entD  = (int*)alloc((size_t)Ee * 4);
  float* rdegN = (float*)alloc((size_t)Nn * 4);
  int* bsum  = (int*)alloc(2048 * 4);
  if (avail == 0 && wp > (char*)d_ws + ws_size) return;  // ws too small: clean fail

  // node-phase f32 arrays overlay BUF (dead after pools are built): 8 x 25.6MB
  float* er  = (float*)BUF + 0 * NH;
  float* ae  = (float*)BUF + 1 * NH;
  float* hn  = (float*)BUF + 2 * NH;
  float* hn2 = (float*)BUF + 3 * NH;
  float* qb  = (float*)BUF + 4 * NH;
  float* kb  = (float*)BUF + 5 * NH;
  float* vb  = (float*)BUF + 6 * NH;
  float* tmp = (float*)BUF + 7 * NH;
  // T (25.6MB) overlays entBs+entBw (contiguous, dead after pool2 consumes them)
  float* T = (float*)entBs;

  auto cdiv = [](long a, long b) { return (int)((a + b - 1) / b); };
  auto scan = [&](int* cnt, int* ptr, int n, int total) {
    int nb = cdiv(n, 1024);
    k_scan1<<<nb, 256, 0, stream>>>(cnt, ptr, bsum, n);
    k_scan2<<<1, 1024, 0, stream>>>(bsum, nb);
    k_scan3<<<cdiv(n, 256), 256, 0, stream>>>(ptr, bsum, n, total);
  };

  const int gLG = cdiv(LGEe, 256), gEe = cdiv(Ee, 256);

  // ---- CSR A: line-graph by dst_lg (E segments) ----
  hipMemsetAsync(cntA, 0, (size_t)Ee * 4, stream);
  k_count_direct<<<gLG, 256, 0, stream>>>(dst_lg, cntA, LGEe);
  scan(cntA, ptrA, Ee, LGEe);
  hipMemsetAsync(cntA, 0, (size_t)Ee * 4, stream);
  k_fillA<<<gLG, 256, 0, stream>>>(dst_lg, src_lg, ptrA, cntA, entA, LGEe);

  // ---- CSR B: composed H[b][dst_lg[m]] (N segments, 2*LGE entries) ----
  hipMemsetAsync(cntB, 0, (size_t)Nn * 4, stream);
  k_count_comp<<<gLG, 256, 0, stream>>>(H0, dst_lg, cntB, LGEe);
  k_count_comp<<<gLG, 256, 0, stream>>>(H1, dst_lg, cntB, LGEe);
  scan(cntB, ptrB, Nn, 2 * LGEe);
  hipMemsetAsync(cntB, 0, (size_t)Nn * 4, stream);
  k_fillB<<<gLG, 256, 0, stream>>>(H0, dst_lg, src_lg, ptrA, ptrB, cntB, entBs, entBw, LGEe);
  k_fillB<<<gLG, 256, 0, stream>>>(H1, dst_lg, src_lg, ptrA, ptrB, cntB, entBs, entBw, LGEe);

  // ---- CSR C: H incidence (N segments, 2*E entries, value = edge id) ----
  hipMemsetAsync(cntC, 0, (size_t)Nn * 4, stream);
  k_count_direct<<<gEe, 256, 0, stream>>>(H0, cntC, Ee);
  k_count_direct<<<gEe, 256, 0, stream>>>(H1, cntC, Ee);
  scan(cntC, ptrC, Nn, 2 * Ee);
  hipMemsetAsync(cntC, 0, (size_t)Nn * 4, stream);
  k_fillC<<<gEe, 256, 0, stream>>>(H0, ptrC, cntC, entC, Ee);
  k_fillC<<<gEe, 256, 0, stream>>>(H1, ptrC, cntC, entC, Ee);

  // ---- CSR D: raw graph by dst (N segments, E entries, value = src) ----
  hipMemsetAsync(cntD, 0, (size_t)Nn * 4, stream);
  k_count_direct<<<gEe, 256, 0, stream>>>(dst, cntD, Ee);
  scan(cntD, ptrD, Nn, Ee);
  hipMemsetAsync(cntD, 0, (size_t)Nn * 4, stream);
  k_fillD<<<gEe, 256, 0, stream>>>(dst, src, ptrD, cntD, entD, Ee);
  k_rdeg<<<cdiv(Nn, 256), 256, 0, stream>>>(ptrC, rdegN, Nn);

  const int gM64  = cdiv(Nn, 64);                       // 782
  const int gW    = cdiv(Nn, 4);                        // 12500
  const int gP2   = cdiv(cdiv(2 * LGEe, 256), 4);       // 3125
  const int gP1   = cdiv(cdiv(2 * Ee, 256), 4);         // 1563
  const int gPf   = cdiv(cdiv(Ee, 256), 4);             // 782

  // ---- TSA layer 1, fused self+nbr -> BUF (bf16, pre-relu), split-bf16 MFMA ----
  k_tsa1<<<Ee / 64, 256, 0, stream>>>(et, ptrA, entA, W_tsa1_s, W_tsa1_n, BUF);

  // ---- TSA layer 2 + EdgeToNode via balanced chunked pooling + MFMA GEMMs ----
  hipMemsetAsync(agg, 0, NH * 4, stream);
  k_poolb<<<gP2, 256, 0, stream>>>(ptrB, entBs, entBw, BUF, agg, Nn, 2 * LGEe);
  k_mgemm<0><<<gM64, 256, 0, stream>>>(Nn, agg, 128, W_tsa2_n, nullptr, nullptr, 0, 0, T, nullptr, 0);
  hipMemsetAsync(agg, 0, NH * 4, stream);
  k_poolb<<<gP1, 256, 0, stream>>>(ptrC, entC, nullptr, BUF, agg, Nn, 2 * Ee);
  k_mgemm<0><<<gM64, 256, 0, stream>>>(Nn, agg, 128, W_tsa2_s, nullptr, nullptr, 0, 0, T, nullptr, 1);
  // node_e = leaky(rdeg * T @ W_etn); er = node_e @ W_eg_lin
  k_mgemm<0><<<gM64, 256, 0, stream>>>(Nn, T, 128, W_etn, nullptr, rdegN, 0, 2, tmp, nullptr, 0);
  k_mgemm<0><<<gM64, 256, 0, stream>>>(Nn, tmp, 128, W_eg_lin, nullptr, nullptr, 0, 0, er, nullptr, 0);

  // ---- edge_aggr SAGE (dual: ae = er@Ws, tmp = er@Wn) ----
  k_mgemm<1><<<gM64, 256, 0, stream>>>(Nn, er, 128, W_ea_s, W_ea_n, nullptr, 0, 0, ae, tmp, 0);
  k_poolf<<<gPf, 256, 0, stream>>>(ptrD, entD, tmp, ae, Nn, Ee);

  // ---- attr_node_model (dual pairs; hn kept pre-relu, relu applied on read) ----
  k_mgemm<1><<<gM64, 256, 0, stream>>>(Nn, x, 256, W_an1_s, W_an1_n, nullptr, 0, 0, hn, tmp, 0);
  k_poolf<<<gPf, 256, 0, stream>>>(ptrD, entD, tmp, hn, Nn, Ee);
  k_mgemm<1><<<gM64, 256, 0, stream>>>(Nn, hn, 128, W_an2_s, W_an2_n, nullptr, 1, 0, hn2, tmp, 0);
  k_poolf<<<gPf, 256, 0, stream>>>(ptrD, entD, tmp, hn2, Nn, Ee);

  // ---- MixAttention (fused online softmax; out accumulated into hn2) ----
  k_mgemm<0><<<gM64, 256, 0, stream>>>(Nn, hn2, 128, Wq, nullptr, nullptr, 0, 0, qb, nullptr, 0);
  k_mgemm<1><<<gM64, 256, 0, stream>>>(Nn, ae, 128, Wk, Wv, nullptr, 0, 0, kb, vb, 0);
  k_attn<<<gW, 256, 0, stream>>>(ptrD, entD, qb, kb, vb, hn2, Nn);

  // ---- classifier + log_softmax ----
  k_out<<<gW, 256, 0, stream>>>(hn2, W_out, out, Nn);
}